// Round 8
// baseline (337.590 us; speedup 1.0000x reference)
//
#include <hip/hip_runtime.h>
#include <hip/hip_bf16.h>
#include <math.h>

// ---------------------------------------------------------------------------
// HyperParamNet — round 8.
// Round-7: kC fixed (off top-5). kA 219us: VALUBusy 30%, Occ 31%, no pipe
// saturated -> latency-bound on lgkm chains + per-chunk staging recompute.
// This round (kA only):
//   1. __launch_bounds__(256,4): LDS 38.5KB*4 = 154KB/CU fits -> 4 blocks/CU.
//   2. conv1 weights repacked [ch-quad][tap][4ch] -> ds_read_b128 (18 vs 36
//      reads/group), q-outer loop, named accumulators (static idx).
//   3. staging (g,r,c,valid,offset) hoisted out of the chunk loop; bf16 pack
//      via v_cvt_pk_bf16_f32 (1 instr / 2 values vs 4-op manual RNE).
// kB / kC / kInit unchanged.
// ---------------------------------------------------------------------------

using s16x8 = __attribute__((ext_vector_type(8))) short;
using f32x4 = __attribute__((ext_vector_type(4))) float;

__device__ __forceinline__ float leaky(float x) {
    return x >= 0.f ? x : 0.01f * x;
}

// float -> bf16 bits, round-to-nearest-even (used in one-time staging only)
__device__ __forceinline__ unsigned short f2bf(float f) {
    unsigned x = __float_as_uint(f);
    return (unsigned short)((x + 0x7FFFu + ((x >> 16) & 1u)) >> 16);
}

// ---------------------------------------------------------------------------
// kInit: zero ta accumulators + transpose bw1/bw2 to [tap][o] in ws.
// ---------------------------------------------------------------------------
__global__ void kInit(float* __restrict__ sums, unsigned* __restrict__ maxu,
                      const float* __restrict__ bw1, const float* __restrict__ bw2,
                      float* __restrict__ wT1g, float* __restrict__ wT2g) {
    int t = threadIdx.x;   // 256
    sums[t] = 0.f;
    maxu[t] = 0u;
    for (int i = t; i < 288; i += 256) {      // wT1g[(ic*9+k)*16 + o]
        int o = i & 15, rest = i >> 4;        // rest = ic*9+k, ic<2
        int ic = rest / 9, k = rest - ic * 9;
        wT1g[i] = bw1[(o * 2 + ic) * 9 + k];
    }
    for (int i = t; i < 2304; i += 256) {     // wT2g[(ic*9+k)*16 + o]
        int o = i & 15, rest = i >> 4;        // ic<16
        int ic = rest / 9, k = rest - ic * 9;
        wT2g[i] = bw2[(o * 16 + ic) * 9 + k];
    }
}

// ---------------------------------------------------------------------------
// kA: fused conv1(grouped 3x3, VALU) + conv2(1x1, MFMA) + xc + ta reduce.
// Grid (16,32,8): 8-row x 16-col tiles. Block 256 = 4 waves; wave wv owns
// rows 2wv..2wv+1 (pg), lane (col,lg): pixel x=col, k-slice lg.
// ---------------------------------------------------------------------------
__global__ __launch_bounds__(256, 4) void kA(
    const float* __restrict__ y, const float* __restrict__ mask,
    const float* __restrict__ fw1, const float* __restrict__ fb1,
    const float* __restrict__ fw2, const float* __restrict__ fb2,
    float* __restrict__ xc, float* __restrict__ sums, unsigned* __restrict__ maxu)
{
    __shared__ float2 shH[8 * 180];              // halo (y,mask)       11520B
    __shared__ short  Wl[64 * 136];              // conv2 W bf16 K-pad  17408B
    __shared__ __align__(16) float2 w1q4[1008];  // conv1 W [c4][q][4]   8064B
    __shared__ __align__(16) float  fbl[112];    // conv1 bias            448B
    __shared__ float  red[4 * 32 * 2];           // ta partials          1024B

    const int b  = blockIdx.z;
    const int h0 = blockIdx.y << 3;
    const int w0 = blockIdx.x << 4;
    const int tid = threadIdx.x;
    const int wv = tid >> 6, ln = tid & 63;
    const int col = ln & 15, lg = ln >> 4;

    // ---- one-time weight staging ----
    for (int i = tid; i < 1008; i += 256) {      // w1q4[(c4*9+q)*4 + cl]
        int c4 = i / 36, rem = i - c4 * 36;
        int q = rem >> 2, cl = rem & 3;
        int ch = c4 * 4 + cl;
        w1q4[i] = make_float2(fw1[ch * 18 + q], fw1[ch * 18 + 9 + q]);
    }
    if (tid < 112) fbl[tid] = fb1[tid];
    for (int i = tid; i < 64 * 136; i += 256) {
        int o = i / 136, k = i - o * 136;
        Wl[i] = (k < 112) ? (short)f2bf(fw2[o * 112 + k]) : (short)0;
    }

    // ---- per-thread staging slots, hoisted out of the chunk loop ----
    int  sOff[6];    // global offset for chunk 0 (channel base added per s)
    bool sOK[6];
    #pragma unroll
    for (int j = 0; j < 6; ++j) {
        const int i = tid + j * 256;
        int g = i / 180, rem = i - g * 180;
        int r = rem / 18, c = rem - r * 18;
        int gh = h0 + r - 1, gw = w0 + c - 1;
        sOK[j]  = (i < 1440) && ((unsigned)gh < 256u) && ((unsigned)gw < 256u);
        sOff[j] = ((b * 28 + g) << 16) + (gh << 8) + gw;
    }

    // ---- C accumulators, init with conv2 bias ----
    f32x4 acc[2][4];   // [pg][t]
    #pragma unroll
    for (int t = 0; t < 4; ++t) {
        #pragma unroll
        for (int r = 0; r < 4; ++r) {
            float bv = fb2[t * 16 + lg * 4 + r];
            acc[0][t][r] = bv;
            acc[1][t][r] = bv;
        }
    }

    // ---- K-chunk loop: 8 groups (32 temp-channels) per chunk ----
    #pragma unroll 1
    for (int s = 0; s < 4; ++s) {
        if (s) __syncthreads();            // prev compute done reading shH
        const int TOT = ((s == 3) ? 4 : 8) * 180;
        const int chAdd = (s * 8) << 16;
        #pragma unroll
        for (int j = 0; j < 6; ++j) {
            const int i = tid + j * 256;
            if (i < TOT) {
                float2 v = make_float2(0.f, 0.f);
                if (sOK[j]) {
                    size_t o = (size_t)(sOff[j] + chAdd);
                    v.x = y[o];
                    v.y = mask[o];
                }
                shH[i] = v;
            }
        }
        __syncthreads();

        // A-fragments (layout proven round 3)
        s16x8 A[4];
        #pragma unroll
        for (int t = 0; t < 4; ++t)
            A[t] = *(const s16x8*)&Wl[(t * 16 + col) * 136 + s * 32 + lg * 8];

        // B-fragments via conv1, built as packed bf16 words
        unsigned Bu[2][4] = {{0u,0u,0u,0u},{0u,0u,0u,0u}};

        if (s < 3 || lg < 2) {             // s=3, lg>=2 -> channels >=112
            #pragma unroll
            for (int gidx = 0; gidx < 2; ++gidx) {
                const int gl = 2 * lg + gidx;      // local group 0..7
                const int c4 = s * 8 + gl;         // global channel-quad
                float2 hl[4][3];
                const float2* hb = &shH[gl * 180 + (2 * wv) * 18 + col];
                #pragma unroll
                for (int rr = 0; rr < 4; ++rr)
                    #pragma unroll
                    for (int cc = 0; cc < 3; ++cc)
                        hl[rr][cc] = hb[rr * 18 + cc];

                const f32x4 bias4 = *(const f32x4*)&fbl[c4 * 4];
                float a[4][2];
                #pragma unroll
                for (int jj = 0; jj < 4; ++jj) {
                    a[jj][0] = bias4[jj];
                    a[jj][1] = bias4[jj];
                }
                const f32x4* wquad = (const f32x4*)&w1q4[c4 * 36];
                #pragma unroll
                for (int q = 0; q < 9; ++q) {
                    const f32x4 wa = wquad[2 * q];       // ch0,ch1 (y,m)
                    const f32x4 wb = wquad[2 * q + 1];   // ch2,ch3 (y,m)
                    #pragma unroll
                    for (int pg = 0; pg < 2; ++pg) {
                        const float2 h = hl[pg + q / 3][q % 3];
                        a[0][pg] += wa[0] * h.x + wa[1] * h.y;
                        a[1][pg] += wa[2] * h.x + wa[3] * h.y;
                        a[2][pg] += wb[0] * h.x + wb[1] * h.y;
                        a[3][pg] += wb[2] * h.x + wb[3] * h.y;
                    }
                }
                #pragma unroll
                for (int pg = 0; pg < 2; ++pg) {
                    const float r0 = fmaxf(a[0][pg], 0.f);
                    const float r1 = fmaxf(a[1][pg], 0.f);
                    const float r2 = fmaxf(a[2][pg], 0.f);
                    const float r3 = fmaxf(a[3][pg], 0.f);
                    unsigned wlo, whi;
                    asm("v_cvt_pk_bf16_f32 %0, %1, %2" : "=v"(wlo) : "v"(r0), "v"(r1));
                    asm("v_cvt_pk_bf16_f32 %0, %1, %2" : "=v"(whi) : "v"(r2), "v"(r3));
                    Bu[pg][gidx * 2 + 0] = wlo;
                    Bu[pg][gidx * 2 + 1] = whi;
                }
            }
        }

        s16x8 Bf[2];
        #pragma unroll
        for (int pg = 0; pg < 2; ++pg) {
            union { unsigned u[4]; s16x8 v; } cvt;
            cvt.u[0] = Bu[pg][0]; cvt.u[1] = Bu[pg][1];
            cvt.u[2] = Bu[pg][2]; cvt.u[3] = Bu[pg][3];
            Bf[pg] = cvt.v;
        }

        #pragma unroll
        for (int pg = 0; pg < 2; ++pg)
            #pragma unroll
            for (int t = 0; t < 4; ++t)
                acc[pg][t] = __builtin_amdgcn_mfma_f32_16x16x32_bf16(
                                 A[t], Bf[pg], acc[pg][t], 0, 0, 0);
    }

    // ---- epilogue (proven rounds 3-7) ----
    float* xc0 = xc + (((size_t)b * 2) << 16);
    float* xc1 = xc0 + 65536;

    float run_s[2][4], run_m[2][4];
    #pragma unroll
    for (int t = 0; t < 2; ++t)
        #pragma unroll
        for (int r = 0; r < 4; ++r) { run_s[t][r] = 0.f; run_m[t][r] = -3.4e38f; }

    #pragma unroll
    for (int pg = 0; pg < 2; ++pg) {
        float m8 = -3.4e38f, s8 = 0.f;
        #pragma unroll
        for (int t = 2; t < 4; ++t)
            #pragma unroll
            for (int r = 0; r < 4; ++r) {
                float v = acc[pg][t][r];
                m8 = fmaxf(m8, v); s8 += v;
            }
        m8 = fmaxf(m8, __shfl_xor(m8, 16));
        m8 = fmaxf(m8, __shfl_xor(m8, 32));
        s8 += __shfl_xor(s8, 16);
        s8 += __shfl_xor(s8, 32);
        if (ln < 16) {
            int row = h0 + 2 * wv + pg;
            xc0[(row << 8) + w0 + ln] = m8;
            xc1[(row << 8) + w0 + ln] = s8 * (1.f / 32.f);
        }
        #pragma unroll
        for (int t = 0; t < 2; ++t)
            #pragma unroll
            for (int r = 0; r < 4; ++r) {
                float v = acc[pg][t][r];
                run_s[t][r] += v;
                run_m[t][r] = fmaxf(run_m[t][r], v);
            }
    }

    #pragma unroll
    for (int t = 0; t < 2; ++t)
        #pragma unroll
        for (int r = 0; r < 4; ++r) {
            float s = run_s[t][r], m = run_m[t][r];
            #pragma unroll
            for (int off = 1; off < 16; off <<= 1) {
                s += __shfl_xor(s, off);
                m = fmaxf(m, __shfl_xor(m, off));
            }
            if (col == 0) {
                int ch = t * 16 + lg * 4 + r;
                red[(wv * 32 + ch) * 2 + 0] = s;
                red[(wv * 32 + ch) * 2 + 1] = m;
            }
        }
    __syncthreads();
    if (tid < 32) {
        float s = red[tid*2] + red[(32+tid)*2] + red[(64+tid)*2] + red[(96+tid)*2];
        float m = fmaxf(fmaxf(red[tid*2+1], red[(32+tid)*2+1]),
                        fmaxf(red[(64+tid)*2+1], red[(96+tid)*2+1]));
        atomicAdd(&sums[b*32 + tid], s);
        unsigned ub  = __float_as_uint(m);
        unsigned key = (ub & 0x80000000u) ? ~ub : (ub | 0x80000000u);
        atomicMax(&maxu[b*32 + tid], key);
    }
}

// ---------------------------------------------------------------------------
// Kernel B: finish ta mean/max, run pgm MLP on both, alpha = sum.
// ---------------------------------------------------------------------------
__global__ __launch_bounds__(256) void kB(
    const float* __restrict__ sums, const unsigned* __restrict__ maxu,
    const float* __restrict__ aw1, const float* __restrict__ ab1,
    const float* __restrict__ aw2, const float* __restrict__ ab2,
    const float* __restrict__ aw3, const float* __restrict__ ab3,
    float* __restrict__ out)
{
    __shared__ float xa[8][32], xm[8][32], h1a[8][32], h1m[8][32];
    const int tid = threadIdx.x;
    const int b = tid >> 5, i = tid & 31;

    xa[b][i] = sums[b*32 + i] * (1.f/65536.f);
    unsigned u = maxu[b*32 + i];
    unsigned bits = (u & 0x80000000u) ? (u ^ 0x80000000u) : ~u;
    xm[b][i] = __uint_as_float(bits);
    __syncthreads();

    float sa = ab1[i], sm = ab1[i];
    #pragma unroll
    for (int j = 0; j < 32; ++j) {
        float w = aw1[i*32 + j];
        sa += w * xa[b][j]; sm += w * xm[b][j];
    }
    __syncthreads();
    h1a[b][i] = leaky(sa); h1m[b][i] = leaky(sm);
    __syncthreads();

    sa = ab2[i]; sm = ab2[i];
    #pragma unroll
    for (int j = 0; j < 32; ++j) {
        float w = aw2[i*32 + j];
        sa += w * h1a[b][j]; sm += w * h1m[b][j];
    }
    float h2a = leaky(sa), h2m = leaky(sm);

    float pa = aw3[i] * h2a, pm = aw3[i] * h2m;
    #pragma unroll
    for (int off = 16; off > 0; off >>= 1) {
        pa += __shfl_xor(pa, off);
        pm += __shfl_xor(pm, off);
    }
    if (i == 0) {
        float za = fmaxf(pa + ab3[0], 0.f) + 1e-6f;
        float zm = fmaxf(pm + ab3[0], 0.f) + 1e-6f;
        out[b] = za + zm;
    }
}

// ---------------------------------------------------------------------------
// kC: fused beta chain, spill-free (round-7 proven).
// ---------------------------------------------------------------------------
__global__ __launch_bounds__(256, 3) void kC(
    const float* __restrict__ xc,
    const float* __restrict__ wT1g, const float* __restrict__ bb1,
    const float* __restrict__ wT2g, const float* __restrict__ bb2,
    const float* __restrict__ bw3, const float* __restrict__ bb3,
    float* __restrict__ betaout)
{
    __shared__ float shX[2 * 484];     // xc halo [2][22][22]    3872B
    __shared__ float shB1[16 * 400];   // b1 [o][20][20]        25600B
    __shared__ float shB2[16 * 324];   // b2 [o][18][18]        20736B

    const int b  = blockIdx.z;
    const int h0 = blockIdx.y << 4;
    const int w0 = blockIdx.x << 4;
    const int tid = threadIdx.x;

    for (int i = tid; i < 968; i += 256) {
        int ch = i / 484, rem = i - ch * 484;
        int r = rem / 22, c = rem - r * 22;
        int gh = h0 + r - 3, gw = w0 + c - 3;
        float v = 0.f;
        if ((unsigned)gh < 256u && (unsigned)gw < 256u)
            v = xc[(((size_t)b * 2 + ch) << 16) + (gh << 8) + gw];
        shX[i] = v;
    }
    __syncthreads();

    const f32x4 bias1_0 = *(const f32x4*)&bb1[0];
    const f32x4 bias1_1 = *(const f32x4*)&bb1[4];
    const f32x4 bias1_2 = *(const f32x4*)&bb1[8];
    const f32x4 bias1_3 = *(const f32x4*)&bb1[12];
    #pragma unroll 1
    for (int p = tid; p < 400; p += 256) {
        int r1 = p / 20, c1 = p - r1 * 20;
        f32x4 a0 = bias1_0, a1 = bias1_1, a2 = bias1_2, a3 = bias1_3;
        #pragma unroll
        for (int ic = 0; ic < 2; ++ic)
            #pragma unroll
            for (int k = 0; k < 9; ++k) {
                float v = shX[ic * 484 + (r1 + k / 3) * 22 + (c1 + k % 3)];
                const f32x4* wp = (const f32x4*)&wT1g[(ic * 9 + k) << 4];
                a0 += wp[0] * v; a1 += wp[1] * v;
                a2 += wp[2] * v; a3 += wp[3] * v;
            }
        int gh = h0 - 2 + r1, gw = w0 - 2 + c1;
        if (((unsigned)gh < 256u) && ((unsigned)gw < 256u)) {
            shB1[ 0*400+p]=leaky(a0[0]); shB1[ 1*400+p]=leaky(a0[1]);
            shB1[ 2*400+p]=leaky(a0[2]); shB1[ 3*400+p]=leaky(a0[3]);
            shB1[ 4*400+p]=leaky(a1[0]); shB1[ 5*400+p]=leaky(a1[1]);
            shB1[ 6*400+p]=leaky(a1[2]); shB1[ 7*400+p]=leaky(a1[3]);
            shB1[ 8*400+p]=leaky(a2[0]); shB1[ 9*400+p]=leaky(a2[1]);
            shB1[10*400+p]=leaky(a2[2]); shB1[11*400+p]=leaky(a2[3]);
            shB1[12*400+p]=leaky(a3[0]); shB1[13*400+p]=leaky(a3[1]);
            shB1[14*400+p]=leaky(a3[2]); shB1[15*400+p]=leaky(a3[3]);
        } else {
            #pragma unroll
            for (int o = 0; o < 16; ++o) shB1[o*400+p] = 0.f;
        }
    }
    __syncthreads();

    const f32x4 bias2_0 = *(const f32x4*)&bb2[0];
    const f32x4 bias2_1 = *(const f32x4*)&bb2[4];
    const f32x4 bias2_2 = *(const f32x4*)&bb2[8];
    const f32x4 bias2_3 = *(const f32x4*)&bb2[12];
    #pragma unroll 1
    for (int p = tid; p < 324; p += 256) {
        int r2 = p / 18, c2 = p - r2 * 18;
        f32x4 a0 = bias2_0, a1 = bias2_1, a2 = bias2_2, a3 = bias2_3;
        #pragma unroll 2
        for (int ic = 0; ic < 16; ++ic) {
            const float* base = &shB1[ic * 400 + r2 * 20 + c2];
            #pragma unroll
            for (int k = 0; k < 9; ++k) {
                float v = base[(k / 3) * 20 + (k % 3)];
                const f32x4* wp = (const f32x4*)&wT2g[(ic * 9 + k) << 4];
                a0 += wp[0] * v; a1 += wp[1] * v;
                a2 += wp[2] * v; a3 += wp[3] * v;
            }
        }
        int gh = h0 - 1 + r2, gw = w0 - 1 + c2;
        if (((unsigned)gh < 256u) && ((unsigned)gw < 256u)) {
            shB2[ 0*324+p]=leaky(a0[0]); shB2[ 1*324+p]=leaky(a0[1]);
            shB2[ 2*324+p]=leaky(a0[2]); shB2[ 3*324+p]=leaky(a0[3]);
            shB2[ 4*324+p]=leaky(a1[0]); shB2[ 5*324+p]=leaky(a1[1]);
            shB2[ 6*324+p]=leaky(a1[2]); shB2[ 7*324+p]=leaky(a1[3]);
            shB2[ 8*324+p]=leaky(a2[0]); shB2[ 9*324+p]=leaky(a2[1]);
            shB2[10*324+p]=leaky(a2[2]); shB2[11*324+p]=leaky(a2[3]);
            shB2[12*324+p]=leaky(a3[0]); shB2[13*324+p]=leaky(a3[1]);
            shB2[14*324+p]=leaky(a3[2]); shB2[15*324+p]=leaky(a3[3]);
        } else {
            #pragma unroll
            for (int o = 0; o < 16; ++o) shB2[o*324+p] = 0.f;
        }
    }
    __syncthreads();

    {
        int r3 = tid >> 4, c3 = tid & 15;
        float a = bb3[0];
        #pragma unroll 4
        for (int ic = 0; ic < 16; ++ic)
            #pragma unroll
            for (int k = 0; k < 9; ++k)
                a += bw3[ic * 9 + k]
                     * shB2[ic * 324 + (r3 + k / 3) * 18 + (c3 + k % 3)];
        betaout[((size_t)b << 16) + ((h0 + r3) << 8) + (w0 + c3)]
            = 1.f / (1.f + expf(-a));
    }
}

// ---------------------------------------------------------------------------
extern "C" void kernel_launch(void* const* d_in, const int* in_sizes, int n_in,
                              void* d_out, int out_size, void* d_ws, size_t ws_size,
                              hipStream_t stream) {
    const float* y    = (const float*)d_in[0];
    const float* mask = (const float*)d_in[1];
    const float* fw1  = (const float*)d_in[2];
    const float* fb1  = (const float*)d_in[3];
    const float* fw2  = (const float*)d_in[4];
    const float* fb2  = (const float*)d_in[5];
    const float* aw1  = (const float*)d_in[6];
    const float* ab1  = (const float*)d_in[7];
    const float* aw2  = (const float*)d_in[8];
    const float* ab2  = (const float*)d_in[9];
    const float* aw3  = (const float*)d_in[10];
    const float* ab3  = (const float*)d_in[11];
    const float* bw1  = (const float*)d_in[12];
    const float* bb1  = (const float*)d_in[13];
    const float* bw2  = (const float*)d_in[14];
    const float* bb2  = (const float*)d_in[15];
    const float* bw3  = (const float*)d_in[16];
    const float* bb3  = (const float*)d_in[17];
    float* out = (float*)d_out;

    char* ws = (char*)d_ws;
    float*    sums = (float*)ws;                 // 1 KB
    unsigned* maxu = (unsigned*)(ws + 1024);     // 1 KB
    float*    wT1g = (float*)(ws + 2048);        // 1152 B
    float*    wT2g = (float*)(ws + 3200);        // 9216 B (ends 12416)
    float*    xc   = (float*)(ws + 16384);       // 4 MB

    kInit<<<1, 256, 0, stream>>>(sums, maxu, bw1, bw2, wT1g, wT2g);
    kA<<<dim3(16, 32, 8), 256, 0, stream>>>(y, mask, fw1, fb1, fw2, fb2,
                                            xc, sums, maxu);
    kB<<<1, 256, 0, stream>>>(sums, maxu, aw1, ab1, aw2, ab2, aw3, ab3, out);
    kC<<<dim3(16, 16, 8), 256, 0, stream>>>(xc, wT1g, bb1, wT2g, bb2, bw3, bb3,
                                            out + 8);
}

// Round 9
// 333.624 us; speedup vs baseline: 1.0119x; 1.0119x over previous
//
#include <hip/hip_runtime.h>
#include <hip/hip_bf16.h>
#include <math.h>

// ---------------------------------------------------------------------------
// HyperParamNet — round 9.
// Round-8 regression: launch_bounds(,4) -> VGPR 64 -> spills (WRITE 245MB).
// Re-diagnosis: VALUBusy stuck ~30% across occupancies 22-43% -> per-CU LDS
// pipe + dependent lgkm chains bind; dominant consumer = per-lane conv1
// weight reads (144 ds_read_b128/wave, forced by lg-dependent channels).
// v2 restructure:
//   * conv1: wave-uniform groups (g = wv mod 4) -> readfirstlane ->
//     SCALAR (s_load) weights; results -> bf16 t1 tile in LDS
//     [oct][pix][8ch] (b128-conflict-free).
//   * MFMA phase: B-frag = 1 ds_read_b128 from t1 (8/wave vs 144 weight
//     reads). A-frags/epilogue = proven round-3..8 code.
//   * 2 staging phases (14 groups) instead of 4; LDS 67.3KB, lb(256,2).
// kB / kC / kInit unchanged.
// ---------------------------------------------------------------------------

using s16x8 = __attribute__((ext_vector_type(8))) short;
using f32x4 = __attribute__((ext_vector_type(4))) float;

__device__ __forceinline__ float leaky(float x) {
    return x >= 0.f ? x : 0.01f * x;
}

// float -> bf16 bits, round-to-nearest-even (one-time staging only)
__device__ __forceinline__ unsigned short f2bf(float f) {
    unsigned x = __float_as_uint(f);
    return (unsigned short)((x + 0x7FFFu + ((x >> 16) & 1u)) >> 16);
}

// ---------------------------------------------------------------------------
__global__ void kInit(float* __restrict__ sums, unsigned* __restrict__ maxu,
                      const float* __restrict__ bw1, const float* __restrict__ bw2,
                      float* __restrict__ wT1g, float* __restrict__ wT2g) {
    int t = threadIdx.x;   // 256
    sums[t] = 0.f;
    maxu[t] = 0u;
    for (int i = t; i < 288; i += 256) {
        int o = i & 15, rest = i >> 4;
        int ic = rest / 9, k = rest - ic * 9;
        wT1g[i] = bw1[(o * 2 + ic) * 9 + k];
    }
    for (int i = t; i < 2304; i += 256) {
        int o = i & 15, rest = i >> 4;
        int ic = rest / 9, k = rest - ic * 9;
        wT2g[i] = bw2[(o * 16 + ic) * 9 + k];
    }
}

// ---------------------------------------------------------------------------
// kA v2. Grid (16,32,8): 8x16 tiles. Block 256 = 4 waves.
// conv1: wave wv computes groups {g : g%4==wv} for ALL 128 pixels; lane
// (rr=ln>>4, col=ln&15) owns pixels rows {2rr,2rr+1} at col. Weights scalar.
// MFMA: wave wv owns rows 2wv..2wv+1; lane (col,lq): pixel col, k-slice lq.
// ---------------------------------------------------------------------------
__global__ __launch_bounds__(256, 2) void kA(
    const float* __restrict__ y, const float* __restrict__ mask,
    const float* __restrict__ fw1, const float* __restrict__ fb1,
    const float* __restrict__ fw2, const float* __restrict__ fb2,
    float* __restrict__ xc, float* __restrict__ sums, unsigned* __restrict__ maxu)
{
    __shared__ float2 shH[14 * 180];             // 14-group halo      20160B
    __shared__ short  t1s[14 * 128 * 8];         // t1 [oct][pix][8ch] 28672B
    __shared__ short  Wl[64 * 136];              // conv2 W bf16 K-pad 17408B
    __shared__ float  red[4 * 32 * 2];           // ta partials         1024B

    const int b  = blockIdx.z;
    const int h0 = blockIdx.y << 3;
    const int w0 = blockIdx.x << 4;
    const int tid = threadIdx.x;
    const int wv = tid >> 6, ln = tid & 63;
    const int col = ln & 15, lq = ln >> 4;   // lq: conv1 row-quad / MFMA k-slice

    // ---- stage conv2 weights (bf16, K-padded) ----
    for (int i = tid; i < 64 * 136; i += 256) {
        int o = i / 136, k = i - o * 136;
        Wl[i] = (k < 112) ? (short)f2bf(fw2[o * 112 + k]) : (short)0;
    }

    // ---- hoisted staging slots (2520 entries per phase) ----
    int  sOff[10];
    bool sOK[10];
    #pragma unroll
    for (int j = 0; j < 10; ++j) {
        const int i = tid + j * 256;
        int gl = i / 180, rem = i - gl * 180;
        int r = rem / 18, c = rem - r * 18;
        int gh = h0 + r - 1, gw = w0 + c - 1;
        sOK[j]  = (i < 2520) && ((unsigned)gh < 256u) && ((unsigned)gw < 256u);
        sOff[j] = ((b * 28 + gl) << 16) + (gh << 8) + gw;
    }

    // ---- conv1 in two 14-group phases ----
    #pragma unroll 1
    for (int p = 0; p < 2; ++p) {
        if (p) __syncthreads();            // phase-0 conv1 done reading shH
        const int add = (p * 14) << 16;
        #pragma unroll
        for (int j = 0; j < 10; ++j) {
            const int i = tid + j * 256;
            if (i < 2520) {
                float2 v = make_float2(0.f, 0.f);
                if (sOK[j]) {
                    size_t o = (size_t)(sOff[j] + add);
                    v.x = y[o];
                    v.y = mask[o];
                }
                shH[i] = v;
            }
        }
        __syncthreads();

        // groups of this wave in this phase
        #pragma unroll 1
        for (int g0 = wv; g0 < 28; g0 += 4) {
            if ((g0 / 14) != p) continue;
            const int g  = __builtin_amdgcn_readfirstlane(g0);
            const int gl = g - p * 14;

            // halo window: rows 2rr..2rr+3 (covers output rows 2rr,2rr+1)
            float2 hl[4][3];
            const float2* hb = &shH[gl * 180 + (2 * lq) * 18 + col];
            #pragma unroll
            for (int rr = 0; rr < 4; ++rr)
                #pragma unroll
                for (int cc = 0; cc < 3; ++cc)
                    hl[rr][cc] = hb[rr * 18 + cc];

            const float* wg = fw1 + g * 72;      // scalar (uniform) reads
            float r0[4], r1[4];
            #pragma unroll
            for (int oc = 0; oc < 4; ++oc) {
                float a0 = fb1[4 * g + oc];
                float a1 = a0;
                #pragma unroll
                for (int q = 0; q < 9; ++q) {
                    const float wy = wg[oc * 18 + q];
                    const float wm = wg[oc * 18 + 9 + q];
                    const int dy = q / 3, dx = q % 3;
                    a0 += wy * hl[dy    ][dx].x + wm * hl[dy    ][dx].y;
                    a1 += wy * hl[dy + 1][dx].x + wm * hl[dy + 1][dx].y;
                }
                r0[oc] = fmaxf(a0, 0.f);
                r1[oc] = fmaxf(a1, 0.f);
            }
            unsigned p0lo, p0hi, p1lo, p1hi;
            asm("v_cvt_pk_bf16_f32 %0, %1, %2" : "=v"(p0lo) : "v"(r0[0]), "v"(r0[1]));
            asm("v_cvt_pk_bf16_f32 %0, %1, %2" : "=v"(p0hi) : "v"(r0[2]), "v"(r0[3]));
            asm("v_cvt_pk_bf16_f32 %0, %1, %2" : "=v"(p1lo) : "v"(r1[0]), "v"(r1[1]));
            asm("v_cvt_pk_bf16_f32 %0, %1, %2" : "=v"(p1hi) : "v"(r1[2]), "v"(r1[3]));

            // t1 write: oct=g/2, 4ch half = g&1; pixel rows 2lq, 2lq+1
            const int base0 = (g >> 1) * 1024 + ((2 * lq) * 16 + col) * 8 + (g & 1) * 4;
            *(uint2*)&t1s[base0]       = make_uint2(p0lo, p0hi);
            *(uint2*)&t1s[base0 + 128] = make_uint2(p1lo, p1hi);   // next row (+16px*8)
        }
    }
    __syncthreads();   // t1 + Wl complete

    // ---- MFMA phase: C[64][16] per (wave,pg) ----
    f32x4 acc[2][4];   // [pg][t]
    #pragma unroll
    for (int t = 0; t < 4; ++t) {
        #pragma unroll
        for (int r = 0; r < 4; ++r) {
            float bv = fb2[t * 16 + lq * 4 + r];
            acc[0][t][r] = bv;
            acc[1][t][r] = bv;
        }
    }

    #pragma unroll
    for (int s = 0; s < 4; ++s) {
        s16x8 A[4];
        #pragma unroll
        for (int t = 0; t < 4; ++t)
            A[t] = *(const s16x8*)&Wl[(t * 16 + col) * 136 + s * 32 + lq * 8];

        #pragma unroll
        for (int pg = 0; pg < 2; ++pg) {
            s16x8 Bf;
            if (s == 3 && lq >= 2) {
                #pragma unroll
                for (int j = 0; j < 8; ++j) Bf[j] = 0;
            } else {
                const int oct = 4 * s + lq;
                Bf = *(const s16x8*)&t1s[oct * 1024 + ((2 * wv + pg) * 16 + col) * 8];
            }
            #pragma unroll
            for (int t = 0; t < 4; ++t)
                acc[pg][t] = __builtin_amdgcn_mfma_f32_16x16x32_bf16(
                                 A[t], Bf, acc[pg][t], 0, 0, 0);
        }
    }

    // ---- epilogue (proven rounds 3-8; lq == lg) ----
    float* xc0 = xc + (((size_t)b * 2) << 16);
    float* xc1 = xc0 + 65536;

    float run_s[2][4], run_m[2][4];
    #pragma unroll
    for (int t = 0; t < 2; ++t)
        #pragma unroll
        for (int r = 0; r < 4; ++r) { run_s[t][r] = 0.f; run_m[t][r] = -3.4e38f; }

    #pragma unroll
    for (int pg = 0; pg < 2; ++pg) {
        float m8 = -3.4e38f, s8 = 0.f;
        #pragma unroll
        for (int t = 2; t < 4; ++t)
            #pragma unroll
            for (int r = 0; r < 4; ++r) {
                float v = acc[pg][t][r];
                m8 = fmaxf(m8, v); s8 += v;
            }
        m8 = fmaxf(m8, __shfl_xor(m8, 16));
        m8 = fmaxf(m8, __shfl_xor(m8, 32));
        s8 += __shfl_xor(s8, 16);
        s8 += __shfl_xor(s8, 32);
        if (ln < 16) {
            int row = h0 + 2 * wv + pg;
            xc0[(row << 8) + w0 + ln] = m8;
            xc1[(row << 8) + w0 + ln] = s8 * (1.f / 32.f);
        }
        #pragma unroll
        for (int t = 0; t < 2; ++t)
            #pragma unroll
            for (int r = 0; r < 4; ++r) {
                float v = acc[pg][t][r];
                run_s[t][r] += v;
                run_m[t][r] = fmaxf(run_m[t][r], v);
            }
    }

    #pragma unroll
    for (int t = 0; t < 2; ++t)
        #pragma unroll
        for (int r = 0; r < 4; ++r) {
            float s = run_s[t][r], m = run_m[t][r];
            #pragma unroll
            for (int off = 1; off < 16; off <<= 1) {
                s += __shfl_xor(s, off);
                m = fmaxf(m, __shfl_xor(m, off));
            }
            if (col == 0) {
                int ch = t * 16 + lq * 4 + r;
                red[(wv * 32 + ch) * 2 + 0] = s;
                red[(wv * 32 + ch) * 2 + 1] = m;
            }
        }
    __syncthreads();
    if (tid < 32) {
        float s = red[tid*2] + red[(32+tid)*2] + red[(64+tid)*2] + red[(96+tid)*2];
        float m = fmaxf(fmaxf(red[tid*2+1], red[(32+tid)*2+1]),
                        fmaxf(red[(64+tid)*2+1], red[(96+tid)*2+1]));
        atomicAdd(&sums[b*32 + tid], s);
        unsigned ub  = __float_as_uint(m);
        unsigned key = (ub & 0x80000000u) ? ~ub : (ub | 0x80000000u);
        atomicMax(&maxu[b*32 + tid], key);
    }
}

// ---------------------------------------------------------------------------
// Kernel B: finish ta mean/max, run pgm MLP on both, alpha = sum.
// ---------------------------------------------------------------------------
__global__ __launch_bounds__(256) void kB(
    const float* __restrict__ sums, const unsigned* __restrict__ maxu,
    const float* __restrict__ aw1, const float* __restrict__ ab1,
    const float* __restrict__ aw2, const float* __restrict__ ab2,
    const float* __restrict__ aw3, const float* __restrict__ ab3,
    float* __restrict__ out)
{
    __shared__ float xa[8][32], xm[8][32], h1a[8][32], h1m[8][32];
    const int tid = threadIdx.x;
    const int b = tid >> 5, i = tid & 31;

    xa[b][i] = sums[b*32 + i] * (1.f/65536.f);
    unsigned u = maxu[b*32 + i];
    unsigned bits = (u & 0x80000000u) ? (u ^ 0x80000000u) : ~u;
    xm[b][i] = __uint_as_float(bits);
    __syncthreads();

    float sa = ab1[i], sm = ab1[i];
    #pragma unroll
    for (int j = 0; j < 32; ++j) {
        float w = aw1[i*32 + j];
        sa += w * xa[b][j]; sm += w * xm[b][j];
    }
    __syncthreads();
    h1a[b][i] = leaky(sa); h1m[b][i] = leaky(sm);
    __syncthreads();

    sa = ab2[i]; sm = ab2[i];
    #pragma unroll
    for (int j = 0; j < 32; ++j) {
        float w = aw2[i*32 + j];
        sa += w * h1a[b][j]; sm += w * h1m[b][j];
    }
    float h2a = leaky(sa), h2m = leaky(sm);

    float pa = aw3[i] * h2a, pm = aw3[i] * h2m;
    #pragma unroll
    for (int off = 16; off > 0; off >>= 1) {
        pa += __shfl_xor(pa, off);
        pm += __shfl_xor(pm, off);
    }
    if (i == 0) {
        float za = fmaxf(pa + ab3[0], 0.f) + 1e-6f;
        float zm = fmaxf(pm + ab3[0], 0.f) + 1e-6f;
        out[b] = za + zm;
    }
}

// ---------------------------------------------------------------------------
// kC: fused beta chain, spill-free (round-7 proven).
// ---------------------------------------------------------------------------
__global__ __launch_bounds__(256, 3) void kC(
    const float* __restrict__ xc,
    const float* __restrict__ wT1g, const float* __restrict__ bb1,
    const float* __restrict__ wT2g, const float* __restrict__ bb2,
    const float* __restrict__ bw3, const float* __restrict__ bb3,
    float* __restrict__ betaout)
{
    __shared__ float shX[2 * 484];     // xc halo [2][22][22]    3872B
    __shared__ float shB1[16 * 400];   // b1 [o][20][20]        25600B
    __shared__ float shB2[16 * 324];   // b2 [o][18][18]        20736B

    const int b  = blockIdx.z;
    const int h0 = blockIdx.y << 4;
    const int w0 = blockIdx.x << 4;
    const int tid = threadIdx.x;

    for (int i = tid; i < 968; i += 256) {
        int ch = i / 484, rem = i - ch * 484;
        int r = rem / 22, c = rem - r * 22;
        int gh = h0 + r - 3, gw = w0 + c - 3;
        float v = 0.f;
        if ((unsigned)gh < 256u && (unsigned)gw < 256u)
            v = xc[(((size_t)b * 2 + ch) << 16) + (gh << 8) + gw];
        shX[i] = v;
    }
    __syncthreads();

    const f32x4 bias1_0 = *(const f32x4*)&bb1[0];
    const f32x4 bias1_1 = *(const f32x4*)&bb1[4];
    const f32x4 bias1_2 = *(const f32x4*)&bb1[8];
    const f32x4 bias1_3 = *(const f32x4*)&bb1[12];
    #pragma unroll 1
    for (int p = tid; p < 400; p += 256) {
        int r1 = p / 20, c1 = p - r1 * 20;
        f32x4 a0 = bias1_0, a1 = bias1_1, a2 = bias1_2, a3 = bias1_3;
        #pragma unroll
        for (int ic = 0; ic < 2; ++ic)
            #pragma unroll
            for (int k = 0; k < 9; ++k) {
                float v = shX[ic * 484 + (r1 + k / 3) * 22 + (c1 + k % 3)];
                const f32x4* wp = (const f32x4*)&wT1g[(ic * 9 + k) << 4];
                a0 += wp[0] * v; a1 += wp[1] * v;
                a2 += wp[2] * v; a3 += wp[3] * v;
            }
        int gh = h0 - 2 + r1, gw = w0 - 2 + c1;
        if (((unsigned)gh < 256u) && ((unsigned)gw < 256u)) {
            shB1[ 0*400+p]=leaky(a0[0]); shB1[ 1*400+p]=leaky(a0[1]);
            shB1[ 2*400+p]=leaky(a0[2]); shB1[ 3*400+p]=leaky(a0[3]);
            shB1[ 4*400+p]=leaky(a1[0]); shB1[ 5*400+p]=leaky(a1[1]);
            shB1[ 6*400+p]=leaky(a1[2]); shB1[ 7*400+p]=leaky(a1[3]);
            shB1[ 8*400+p]=leaky(a2[0]); shB1[ 9*400+p]=leaky(a2[1]);
            shB1[10*400+p]=leaky(a2[2]); shB1[11*400+p]=leaky(a2[3]);
            shB1[12*400+p]=leaky(a3[0]); shB1[13*400+p]=leaky(a3[1]);
            shB1[14*400+p]=leaky(a3[2]); shB1[15*400+p]=leaky(a3[3]);
        } else {
            #pragma unroll
            for (int o = 0; o < 16; ++o) shB1[o*400+p] = 0.f;
        }
    }
    __syncthreads();

    const f32x4 bias2_0 = *(const f32x4*)&bb2[0];
    const f32x4 bias2_1 = *(const f32x4*)&bb2[4];
    const f32x4 bias2_2 = *(const f32x4*)&bb2[8];
    const f32x4 bias2_3 = *(const f32x4*)&bb2[12];
    #pragma unroll 1
    for (int p = tid; p < 324; p += 256) {
        int r2 = p / 18, c2 = p - r2 * 18;
        f32x4 a0 = bias2_0, a1 = bias2_1, a2 = bias2_2, a3 = bias2_3;
        #pragma unroll 2
        for (int ic = 0; ic < 16; ++ic) {
            const float* base = &shB1[ic * 400 + r2 * 20 + c2];
            #pragma unroll
            for (int k = 0; k < 9; ++k) {
                float v = base[(k / 3) * 20 + (k % 3)];
                const f32x4* wp = (const f32x4*)&wT2g[(ic * 9 + k) << 4];
                a0 += wp[0] * v; a1 += wp[1] * v;
                a2 += wp[2] * v; a3 += wp[3] * v;
            }
        }
        int gh = h0 - 1 + r2, gw = w0 - 1 + c2;
        if (((unsigned)gh < 256u) && ((unsigned)gw < 256u)) {
            shB2[ 0*324+p]=leaky(a0[0]); shB2[ 1*324+p]=leaky(a0[1]);
            shB2[ 2*324+p]=leaky(a0[2]); shB2[ 3*324+p]=leaky(a0[3]);
            shB2[ 4*324+p]=leaky(a1[0]); shB2[ 5*324+p]=leaky(a1[1]);
            shB2[ 6*324+p]=leaky(a1[2]); shB2[ 7*324+p]=leaky(a1[3]);
            shB2[ 8*324+p]=leaky(a2[0]); shB2[ 9*324+p]=leaky(a2[1]);
            shB2[10*324+p]=leaky(a2[2]); shB2[11*324+p]=leaky(a2[3]);
            shB2[12*324+p]=leaky(a3[0]); shB2[13*324+p]=leaky(a3[1]);
            shB2[14*324+p]=leaky(a3[2]); shB2[15*324+p]=leaky(a3[3]);
        } else {
            #pragma unroll
            for (int o = 0; o < 16; ++o) shB2[o*324+p] = 0.f;
        }
    }
    __syncthreads();

    {
        int r3 = tid >> 4, c3 = tid & 15;
        float a = bb3[0];
        #pragma unroll 4
        for (int ic = 0; ic < 16; ++ic)
            #pragma unroll
            for (int k = 0; k < 9; ++k)
                a += bw3[ic * 9 + k]
                     * shB2[ic * 324 + (r3 + k / 3) * 18 + (c3 + k % 3)];
        betaout[((size_t)b << 16) + ((h0 + r3) << 8) + (w0 + c3)]
            = 1.f / (1.f + expf(-a));
    }
}

// ---------------------------------------------------------------------------
extern "C" void kernel_launch(void* const* d_in, const int* in_sizes, int n_in,
                              void* d_out, int out_size, void* d_ws, size_t ws_size,
                              hipStream_t stream) {
    const float* y    = (const float*)d_in[0];
    const float* mask = (const float*)d_in[1];
    const float* fw1  = (const float*)d_in[2];
    const float* fb1  = (const float*)d_in[3];
    const float* fw2  = (const float*)d_in[4];
    const float* fb2  = (const float*)d_in[5];
    const float* aw1  = (const float*)d_in[6];
    const float* ab1  = (const float*)d_in[7];
    const float* aw2  = (const float*)d_in[8];
    const float* ab2  = (const float*)d_in[9];
    const float* aw3  = (const float*)d_in[10];
    const float* ab3  = (const float*)d_in[11];
    const float* bw1  = (const float*)d_in[12];
    const float* bb1  = (const float*)d_in[13];
    const float* bw2  = (const float*)d_in[14];
    const float* bb2  = (const float*)d_in[15];
    const float* bw3  = (const float*)d_in[16];
    const float* bb3  = (const float*)d_in[17];
    float* out = (float*)d_out;

    char* ws = (char*)d_ws;
    float*    sums = (float*)ws;                 // 1 KB
    unsigned* maxu = (unsigned*)(ws + 1024);     // 1 KB
    float*    wT1g = (float*)(ws + 2048);        // 1152 B
    float*    wT2g = (float*)(ws + 3200);        // 9216 B
    float*    xc   = (float*)(ws + 16384);       // 4 MB

    kInit<<<1, 256, 0, stream>>>(sums, maxu, bw1, bw2, wT1g, wT2g);
    kA<<<dim3(16, 32, 8), 256, 0, stream>>>(y, mask, fw1, fb1, fw2, fb2,
                                            xc, sums, maxu);
    kB<<<1, 256, 0, stream>>>(sums, maxu, aw1, ab1, aw2, ab2, aw3, ab3, out);
    kC<<<dim3(16, 16, 8), 256, 0, stream>>>(xc, wT1g, bb1, wT2g, bb2, bw3, bb3,
                                            out + 8);
}

// Round 10
// 262.950 us; speedup vs baseline: 1.2839x; 1.2688x over previous
//
#include <hip/hip_runtime.h>
#include <hip/hip_bf16.h>
#include <math.h>

// ---------------------------------------------------------------------------
// HyperParamNet — round 10.
// Revert to round-7 kA skeleton (best, 219us), plus:
//   1. kInit pre-packs conv2 W (bf16 [64][128] K-pad) and conv1 W
//      ([c4][q][4ch] float2) in ws. A-fragments load DIRECTLY from global
//      (L2-resident; issued before conv1 -> latency hidden). No Wl LDS, no
//      per-block f2bf, no weight barrier. (~65MB fetch + ~90 instr/thread cut)
//   2. conv1 via v_pk_fma_f32: halo SoA column-major (stride 11) so the two
//      output rows form f32x2 pairs; 72 pk_fma/group vs 144 scalar FMA.
//   3. LDS 22.2KB (was 38.9), lb(256,3).
// kB / kC unchanged (proven).
// ---------------------------------------------------------------------------

using s16x8 = __attribute__((ext_vector_type(8))) short;
using f32x4 = __attribute__((ext_vector_type(4))) float;
using f32x2 = __attribute__((ext_vector_type(2))) float;

__device__ __forceinline__ float leaky(float x) {
    return x >= 0.f ? x : 0.01f * x;
}

__device__ __forceinline__ unsigned short f2bf(float f) {
    unsigned x = __float_as_uint(f);
    return (unsigned short)((x + 0x7FFFu + ((x >> 16) & 1u)) >> 16);
}

// ---------------------------------------------------------------------------
// kInit: zero ta accumulators; transpose bw1/bw2 for kC; pack conv1/conv2
// weights for kA.
// ---------------------------------------------------------------------------
__global__ void kInit(float* __restrict__ sums, unsigned* __restrict__ maxu,
                      const float* __restrict__ bw1, const float* __restrict__ bw2,
                      const float* __restrict__ fw1, const float* __restrict__ fw2,
                      float* __restrict__ wT1g, float* __restrict__ wT2g,
                      float2* __restrict__ wsW1, short* __restrict__ wsW) {
    int t = threadIdx.x;   // 256
    sums[t] = 0.f;
    maxu[t] = 0u;
    for (int i = t; i < 288; i += 256) {
        int o = i & 15, rest = i >> 4;
        int ic = rest / 9, k = rest - ic * 9;
        wT1g[i] = bw1[(o * 2 + ic) * 9 + k];
    }
    for (int i = t; i < 2304; i += 256) {
        int o = i & 15, rest = i >> 4;
        int ic = rest / 9, k = rest - ic * 9;
        wT2g[i] = bw2[(o * 16 + ic) * 9 + k];
    }
    // conv1 weights: wsW1[(c4*36) + q*4 + cl] = (wy, wm) of channel 4*c4+cl
    for (int i = t; i < 1008; i += 256) {
        int c4 = i / 36, rem = i - c4 * 36;
        int q = rem >> 2, cl = rem & 3;
        int ch = c4 * 4 + cl;
        wsW1[i] = make_float2(fw1[ch * 18 + q], fw1[ch * 18 + 9 + q]);
    }
    // conv2 weights: bf16 [64][128], K zero-padded 112..127
    for (int i = t; i < 8192; i += 256) {
        int o = i >> 7, k = i & 127;
        wsW[i] = (k < 112) ? (short)f2bf(fw2[o * 112 + k]) : (short)0;
    }
}

// ---------------------------------------------------------------------------
// kA: fused conv1(grouped 3x3, pk_fma) + conv2(1x1, MFMA) + xc + ta reduce.
// Grid (16,32,8): 8x16 tiles. Block 256 = 4 waves; wave wv owns rows
// 2wv..2wv+1, lane (col,lq): pixel x=col, k-slice lq.
// Halo LDS: SoA (y,m planes), COLUMN-major stride 11: [group][18 cols][11].
// ---------------------------------------------------------------------------
__global__ __launch_bounds__(256, 3) void kA(
    const float* __restrict__ y, const float* __restrict__ mask,
    const float* __restrict__ fb1, const float* __restrict__ fb2,
    const float2* __restrict__ wsW1, const short* __restrict__ wsW,
    float* __restrict__ xc, float* __restrict__ sums, unsigned* __restrict__ maxu)
{
    __shared__ float  shY[8 * 198];              // y halo col-major    6336B
    __shared__ float  shM[8 * 198];              // mask halo           6336B
    __shared__ __align__(16) float2 w1q4[1008];  // conv1 W [c4][q][4]  8064B
    __shared__ __align__(16) float  fbl[112];    // conv1 bias           448B
    __shared__ float  red[4 * 32 * 2];           // ta partials         1024B

    const int b  = blockIdx.z;
    const int h0 = blockIdx.y << 3;
    const int w0 = blockIdx.x << 4;
    const int tid = threadIdx.x;
    const int wv = tid >> 6, ln = tid & 63;
    const int col = ln & 15, lq = ln >> 4;

    // ---- weight staging: plain copies (packed by kInit) ----
    #pragma unroll
    for (int j = 0; j < 4; ++j) {
        int i = tid + j * 256;
        if (i < 1008) w1q4[i] = wsW1[i];
    }
    if (tid < 112) fbl[tid] = fb1[tid];

    // ---- hoisted staging slots (1584 entries/chunk, col-major stride 11) ----
    int  sOff[7];
    bool sOK[7];
    #pragma unroll
    for (int j = 0; j < 7; ++j) {
        const int i = tid + j * 256;
        int gl = i / 198, rem = i - gl * 198;
        int c = rem / 11, r = rem - c * 11;
        int gh = h0 + r - 1, gw = w0 + c - 1;
        sOK[j]  = (i < 1584) && (r < 10) &&
                  ((unsigned)gh < 256u) && ((unsigned)gw < 256u);
        sOff[j] = ((b * 28 + gl) << 16) + (gh << 8) + gw;
    }

    // ---- C accumulators, init with conv2 bias ----
    f32x4 acc[2][4];   // [pg][t]
    #pragma unroll
    for (int t = 0; t < 4; ++t) {
        #pragma unroll
        for (int r = 0; r < 4; ++r) {
            float bv = fb2[t * 16 + lq * 4 + r];
            acc[0][t][r] = bv;
            acc[1][t][r] = bv;
        }
    }

    // ---- K-chunk loop: 8 groups (32 temp-channels) per chunk ----
    #pragma unroll 1
    for (int s = 0; s < 4; ++s) {
        if (s) __syncthreads();            // prev compute done reading halo
        const int TOT = ((s == 3) ? 4 : 8) * 198;
        const int chAdd = (s * 8) << 16;
        #pragma unroll
        for (int j = 0; j < 7; ++j) {
            const int i = tid + j * 256;
            if (i < TOT) {
                float2 v = make_float2(0.f, 0.f);
                if (sOK[j]) {
                    size_t o = (size_t)(sOff[j] + chAdd);
                    v.x = y[o];
                    v.y = mask[o];
                }
                shY[i] = v.x;
                shM[i] = v.y;
            }
        }

        // A-fragments direct from global (L2-resident; latency hidden by conv1)
        s16x8 A[4];
        #pragma unroll
        for (int t = 0; t < 4; ++t)
            A[t] = *(const s16x8*)&wsW[(t * 16 + col) * 128 + s * 32 + lq * 8];

        __syncthreads();                   // halo visible

        // ---- conv1 -> B-fragments (pk_fma over the 2 output rows) ----
        unsigned Bu[2][4] = {{0u,0u,0u,0u},{0u,0u,0u,0u}};

        if (s < 3 || lq < 2) {             // s=3, lq>=2 -> channels >=112
            #pragma unroll
            for (int gidx = 0; gidx < 2; ++gidx) {
                const int gl = 2 * lq + gidx;      // local group 0..7
                const int c4 = s * 8 + gl;         // global channel-quad
                const float* bY = &shY[gl * 198 + col * 11 + 2 * wv];
                const float* bM = &shM[gl * 198 + col * 11 + 2 * wv];
                float hYv[3][4], hMv[3][4];        // [col][row]
                #pragma unroll
                for (int cc = 0; cc < 3; ++cc)
                    #pragma unroll
                    for (int rr = 0; rr < 4; ++rr) {
                        hYv[cc][rr] = bY[cc * 11 + rr];
                        hMv[cc][rr] = bM[cc * 11 + rr];
                    }

                const f32x4 bias4 = *(const f32x4*)&fbl[c4 * 4];
                f32x2 a0 = {bias4[0], bias4[0]};
                f32x2 a1 = {bias4[1], bias4[1]};
                f32x2 a2 = {bias4[2], bias4[2]};
                f32x2 a3 = {bias4[3], bias4[3]};
                const f32x4* wquad = (const f32x4*)&w1q4[c4 * 36];
                #pragma unroll
                for (int q = 0; q < 9; ++q) {
                    const int dy = q / 3, dx = q % 3;
                    const f32x4 wa = wquad[2 * q];       // wy0,wm0,wy1,wm1
                    const f32x4 wb = wquad[2 * q + 1];   // wy2,wm2,wy3,wm3
                    f32x2 hy = {hYv[dx][dy], hYv[dx][dy + 1]};
                    f32x2 hm = {hMv[dx][dy], hMv[dx][dy + 1]};
                    a0 += hy * wa[0] + hm * wa[1];
                    a1 += hy * wa[2] + hm * wa[3];
                    a2 += hy * wb[0] + hm * wb[1];
                    a3 += hy * wb[2] + hm * wb[3];
                }
                const float r00 = fmaxf(a0[0], 0.f), r01 = fmaxf(a1[0], 0.f);
                const float r02 = fmaxf(a2[0], 0.f), r03 = fmaxf(a3[0], 0.f);
                const float r10 = fmaxf(a0[1], 0.f), r11 = fmaxf(a1[1], 0.f);
                const float r12 = fmaxf(a2[1], 0.f), r13 = fmaxf(a3[1], 0.f);
                unsigned p0lo, p0hi, p1lo, p1hi;
                asm("v_cvt_pk_bf16_f32 %0, %1, %2" : "=v"(p0lo) : "v"(r00), "v"(r01));
                asm("v_cvt_pk_bf16_f32 %0, %1, %2" : "=v"(p0hi) : "v"(r02), "v"(r03));
                asm("v_cvt_pk_bf16_f32 %0, %1, %2" : "=v"(p1lo) : "v"(r10), "v"(r11));
                asm("v_cvt_pk_bf16_f32 %0, %1, %2" : "=v"(p1hi) : "v"(r12), "v"(r13));
                Bu[0][gidx * 2 + 0] = p0lo;
                Bu[0][gidx * 2 + 1] = p0hi;
                Bu[1][gidx * 2 + 0] = p1lo;
                Bu[1][gidx * 2 + 1] = p1hi;
            }
        }

        s16x8 Bf[2];
        #pragma unroll
        for (int pg = 0; pg < 2; ++pg) {
            union { unsigned u[4]; s16x8 v; } cvt;
            cvt.u[0] = Bu[pg][0]; cvt.u[1] = Bu[pg][1];
            cvt.u[2] = Bu[pg][2]; cvt.u[3] = Bu[pg][3];
            Bf[pg] = cvt.v;
        }

        #pragma unroll
        for (int pg = 0; pg < 2; ++pg)
            #pragma unroll
            for (int t = 0; t < 4; ++t)
                acc[pg][t] = __builtin_amdgcn_mfma_f32_16x16x32_bf16(
                                 A[t], Bf[pg], acc[pg][t], 0, 0, 0);
    }

    // ---- epilogue (proven rounds 3-9) ----
    float* xc0 = xc + (((size_t)b * 2) << 16);
    float* xc1 = xc0 + 65536;

    float run_s[2][4], run_m[2][4];
    #pragma unroll
    for (int t = 0; t < 2; ++t)
        #pragma unroll
        for (int r = 0; r < 4; ++r) { run_s[t][r] = 0.f; run_m[t][r] = -3.4e38f; }

    #pragma unroll
    for (int pg = 0; pg < 2; ++pg) {
        float m8 = -3.4e38f, s8 = 0.f;
        #pragma unroll
        for (int t = 2; t < 4; ++t)
            #pragma unroll
            for (int r = 0; r < 4; ++r) {
                float v = acc[pg][t][r];
                m8 = fmaxf(m8, v); s8 += v;
            }
        m8 = fmaxf(m8, __shfl_xor(m8, 16));
        m8 = fmaxf(m8, __shfl_xor(m8, 32));
        s8 += __shfl_xor(s8, 16);
        s8 += __shfl_xor(s8, 32);
        if (ln < 16) {
            int row = h0 + 2 * wv + pg;
            xc0[(row << 8) + w0 + ln] = m8;
            xc1[(row << 8) + w0 + ln] = s8 * (1.f / 32.f);
        }
        #pragma unroll
        for (int t = 0; t < 2; ++t)
            #pragma unroll
            for (int r = 0; r < 4; ++r) {
                float v = acc[pg][t][r];
                run_s[t][r] += v;
                run_m[t][r] = fmaxf(run_m[t][r], v);
            }
    }

    #pragma unroll
    for (int t = 0; t < 2; ++t)
        #pragma unroll
        for (int r = 0; r < 4; ++r) {
            float s = run_s[t][r], m = run_m[t][r];
            #pragma unroll
            for (int off = 1; off < 16; off <<= 1) {
                s += __shfl_xor(s, off);
                m = fmaxf(m, __shfl_xor(m, off));
            }
            if (col == 0) {
                int ch = t * 16 + lq * 4 + r;
                red[(wv * 32 + ch) * 2 + 0] = s;
                red[(wv * 32 + ch) * 2 + 1] = m;
            }
        }
    __syncthreads();
    if (tid < 32) {
        float s = red[tid*2] + red[(32+tid)*2] + red[(64+tid)*2] + red[(96+tid)*2];
        float m = fmaxf(fmaxf(red[tid*2+1], red[(32+tid)*2+1]),
                        fmaxf(red[(64+tid)*2+1], red[(96+tid)*2+1]));
        atomicAdd(&sums[b*32 + tid], s);
        unsigned ub  = __float_as_uint(m);
        unsigned key = (ub & 0x80000000u) ? ~ub : (ub | 0x80000000u);
        atomicMax(&maxu[b*32 + tid], key);
    }
}

// ---------------------------------------------------------------------------
// Kernel B: finish ta mean/max, run pgm MLP on both, alpha = sum.
// ---------------------------------------------------------------------------
__global__ __launch_bounds__(256) void kB(
    const float* __restrict__ sums, const unsigned* __restrict__ maxu,
    const float* __restrict__ aw1, const float* __restrict__ ab1,
    const float* __restrict__ aw2, const float* __restrict__ ab2,
    const float* __restrict__ aw3, const float* __restrict__ ab3,
    float* __restrict__ out)
{
    __shared__ float xa[8][32], xm[8][32], h1a[8][32], h1m[8][32];
    const int tid = threadIdx.x;
    const int b = tid >> 5, i = tid & 31;

    xa[b][i] = sums[b*32 + i] * (1.f/65536.f);
    unsigned u = maxu[b*32 + i];
    unsigned bits = (u & 0x80000000u) ? (u ^ 0x80000000u) : ~u;
    xm[b][i] = __uint_as_float(bits);
    __syncthreads();

    float sa = ab1[i], sm = ab1[i];
    #pragma unroll
    for (int j = 0; j < 32; ++j) {
        float w = aw1[i*32 + j];
        sa += w * xa[b][j]; sm += w * xm[b][j];
    }
    __syncthreads();
    h1a[b][i] = leaky(sa); h1m[b][i] = leaky(sm);
    __syncthreads();

    sa = ab2[i]; sm = ab2[i];
    #pragma unroll
    for (int j = 0; j < 32; ++j) {
        float w = aw2[i*32 + j];
        sa += w * h1a[b][j]; sm += w * h1m[b][j];
    }
    float h2a = leaky(sa), h2m = leaky(sm);

    float pa = aw3[i] * h2a, pm = aw3[i] * h2m;
    #pragma unroll
    for (int off = 16; off > 0; off >>= 1) {
        pa += __shfl_xor(pa, off);
        pm += __shfl_xor(pm, off);
    }
    if (i == 0) {
        float za = fmaxf(pa + ab3[0], 0.f) + 1e-6f;
        float zm = fmaxf(pm + ab3[0], 0.f) + 1e-6f;
        out[b] = za + zm;
    }
}

// ---------------------------------------------------------------------------
// kC: fused beta chain, spill-free (round-7 proven).
// ---------------------------------------------------------------------------
__global__ __launch_bounds__(256, 3) void kC(
    const float* __restrict__ xc,
    const float* __restrict__ wT1g, const float* __restrict__ bb1,
    const float* __restrict__ wT2g, const float* __restrict__ bb2,
    const float* __restrict__ bw3, const float* __restrict__ bb3,
    float* __restrict__ betaout)
{
    __shared__ float shX[2 * 484];
    __shared__ float shB1[16 * 400];
    __shared__ float shB2[16 * 324];

    const int b  = blockIdx.z;
    const int h0 = blockIdx.y << 4;
    const int w0 = blockIdx.x << 4;
    const int tid = threadIdx.x;

    for (int i = tid; i < 968; i += 256) {
        int ch = i / 484, rem = i - ch * 484;
        int r = rem / 22, c = rem - r * 22;
        int gh = h0 + r - 3, gw = w0 + c - 3;
        float v = 0.f;
        if ((unsigned)gh < 256u && (unsigned)gw < 256u)
            v = xc[(((size_t)b * 2 + ch) << 16) + (gh << 8) + gw];
        shX[i] = v;
    }
    __syncthreads();

    const f32x4 bias1_0 = *(const f32x4*)&bb1[0];
    const f32x4 bias1_1 = *(const f32x4*)&bb1[4];
    const f32x4 bias1_2 = *(const f32x4*)&bb1[8];
    const f32x4 bias1_3 = *(const f32x4*)&bb1[12];
    #pragma unroll 1
    for (int p = tid; p < 400; p += 256) {
        int r1 = p / 20, c1 = p - r1 * 20;
        f32x4 a0 = bias1_0, a1 = bias1_1, a2 = bias1_2, a3 = bias1_3;
        #pragma unroll
        for (int ic = 0; ic < 2; ++ic)
            #pragma unroll
            for (int k = 0; k < 9; ++k) {
                float v = shX[ic * 484 + (r1 + k / 3) * 22 + (c1 + k % 3)];
                const f32x4* wp = (const f32x4*)&wT1g[(ic * 9 + k) << 4];
                a0 += wp[0] * v; a1 += wp[1] * v;
                a2 += wp[2] * v; a3 += wp[3] * v;
            }
        int gh = h0 - 2 + r1, gw = w0 - 2 + c1;
        if (((unsigned)gh < 256u) && ((unsigned)gw < 256u)) {
            shB1[ 0*400+p]=leaky(a0[0]); shB1[ 1*400+p]=leaky(a0[1]);
            shB1[ 2*400+p]=leaky(a0[2]); shB1[ 3*400+p]=leaky(a0[3]);
            shB1[ 4*400+p]=leaky(a1[0]); shB1[ 5*400+p]=leaky(a1[1]);
            shB1[ 6*400+p]=leaky(a1[2]); shB1[ 7*400+p]=leaky(a1[3]);
            shB1[ 8*400+p]=leaky(a2[0]); shB1[ 9*400+p]=leaky(a2[1]);
            shB1[10*400+p]=leaky(a2[2]); shB1[11*400+p]=leaky(a2[3]);
            shB1[12*400+p]=leaky(a3[0]); shB1[13*400+p]=leaky(a3[1]);
            shB1[14*400+p]=leaky(a3[2]); shB1[15*400+p]=leaky(a3[3]);
        } else {
            #pragma unroll
            for (int o = 0; o < 16; ++o) shB1[o*400+p] = 0.f;
        }
    }
    __syncthreads();

    const f32x4 bias2_0 = *(const f32x4*)&bb2[0];
    const f32x4 bias2_1 = *(const f32x4*)&bb2[4];
    const f32x4 bias2_2 = *(const f32x4*)&bb2[8];
    const f32x4 bias2_3 = *(const f32x4*)&bb2[12];
    #pragma unroll 1
    for (int p = tid; p < 324; p += 256) {
        int r2 = p / 18, c2 = p - r2 * 18;
        f32x4 a0 = bias2_0, a1 = bias2_1, a2 = bias2_2, a3 = bias2_3;
        #pragma unroll 2
        for (int ic = 0; ic < 16; ++ic) {
            const float* base = &shB1[ic * 400 + r2 * 20 + c2];
            #pragma unroll
            for (int k = 0; k < 9; ++k) {
                float v = base[(k / 3) * 20 + (k % 3)];
                const f32x4* wp = (const f32x4*)&wT2g[(ic * 9 + k) << 4];
                a0 += wp[0] * v; a1 += wp[1] * v;
                a2 += wp[2] * v; a3 += wp[3] * v;
            }
        }
        int gh = h0 - 1 + r2, gw = w0 - 1 + c2;
        if (((unsigned)gh < 256u) && ((unsigned)gw < 256u)) {
            shB2[ 0*324+p]=leaky(a0[0]); shB2[ 1*324+p]=leaky(a0[1]);
            shB2[ 2*324+p]=leaky(a0[2]); shB2[ 3*324+p]=leaky(a0[3]);
            shB2[ 4*324+p]=leaky(a1[0]); shB2[ 5*324+p]=leaky(a1[1]);
            shB2[ 6*324+p]=leaky(a1[2]); shB2[ 7*324+p]=leaky(a1[3]);
            shB2[ 8*324+p]=leaky(a2[0]); shB2[ 9*324+p]=leaky(a2[1]);
            shB2[10*324+p]=leaky(a2[2]); shB2[11*324+p]=leaky(a2[3]);
            shB2[12*324+p]=leaky(a3[0]); shB2[13*324+p]=leaky(a3[1]);
            shB2[14*324+p]=leaky(a3[2]); shB2[15*324+p]=leaky(a3[3]);
        } else {
            #pragma unroll
            for (int o = 0; o < 16; ++o) shB2[o*324+p] = 0.f;
        }
    }
    __syncthreads();

    {
        int r3 = tid >> 4, c3 = tid & 15;
        float a = bb3[0];
        #pragma unroll 4
        for (int ic = 0; ic < 16; ++ic)
            #pragma unroll
            for (int k = 0; k < 9; ++k)
                a += bw3[ic * 9 + k]
                     * shB2[ic * 324 + (r3 + k / 3) * 18 + (c3 + k % 3)];
        betaout[((size_t)b << 16) + ((h0 + r3) << 8) + (w0 + c3)]
            = 1.f / (1.f + expf(-a));
    }
}

// ---------------------------------------------------------------------------
extern "C" void kernel_launch(void* const* d_in, const int* in_sizes, int n_in,
                              void* d_out, int out_size, void* d_ws, size_t ws_size,
                              hipStream_t stream) {
    const float* y    = (const float*)d_in[0];
    const float* mask = (const float*)d_in[1];
    const float* fw1  = (const float*)d_in[2];
    const float* fb1  = (const float*)d_in[3];
    const float* fw2  = (const float*)d_in[4];
    const float* fb2  = (const float*)d_in[5];
    const float* aw1  = (const float*)d_in[6];
    const float* ab1  = (const float*)d_in[7];
    const float* aw2  = (const float*)d_in[8];
    const float* ab2  = (const float*)d_in[9];
    const float* aw3  = (const float*)d_in[10];
    const float* ab3  = (const float*)d_in[11];
    const float* bw1  = (const float*)d_in[12];
    const float* bb1  = (const float*)d_in[13];
    const float* bw2  = (const float*)d_in[14];
    const float* bb2  = (const float*)d_in[15];
    const float* bw3  = (const float*)d_in[16];
    const float* bb3  = (const float*)d_in[17];
    float* out = (float*)d_out;

    char* ws = (char*)d_ws;
    float*    sums = (float*)ws;                 // 1 KB
    unsigned* maxu = (unsigned*)(ws + 1024);     // 1 KB
    float*    wT1g = (float*)(ws + 2048);        // 1152 B
    float*    wT2g = (float*)(ws + 3200);        // 9216 B (ends 12416)
    float2*   wsW1 = (float2*)(ws + 12416);      // 8064 B (ends 20480)
    short*    wsW  = (short*)(ws + 20480);       // 16384 B (ends 36864)
    float*    xc   = (float*)(ws + 65536);       // 4 MB

    kInit<<<1, 256, 0, stream>>>(sums, maxu, bw1, bw2, fw1, fw2,
                                 wT1g, wT2g, wsW1, wsW);
    kA<<<dim3(16, 32, 8), 256, 0, stream>>>(y, mask, fb1, fb2, wsW1, wsW,
                                            xc, sums, maxu);
    kB<<<1, 256, 0, stream>>>(sums, maxu, aw1, ab1, aw2, ab2, aw3, ab3, out);
    kC<<<dim3(16, 16, 8), 256, 0, stream>>>(xc, wT1g, bb1, wT2g, bb2, bw3, bb3,
                                            out + 8);
}

// Round 11
// 214.052 us; speedup vs baseline: 1.5771x; 1.2284x over previous
//
#include <hip/hip_runtime.h>
#include <hip/hip_bf16.h>
#include <math.h>

// ---------------------------------------------------------------------------
// HyperParamNet — round 11.
// Round-10 analysis: kA 184us = fetch-rate-limited. FETCH 216MB == 28grp x
// 10 halo rows x 3 lines x 64B x 4096 blocks (matches to 2%), consumed at
// only 1.2TB/s: staging gather is transaction/latency-bound (col-major walk
// = 64 scattered transactions/wave) and stage->barrier->compute serializes
// a full HBM latency per chunk.
// This round (kA staging path only):
//   1. Decouple: ROW-major global walk (coalesced, ~4 segments/wave) with
//      col-major stride-10 LDS store (conv1 pk_fma reads unchanged; even
//      stride -> b64, 2-way banks = free).
//   2. LDS double-buffer + write-late (T14): chunk s+1 loads issue before
//      chunk s compute (14 VGPRs held), regs->LDS into the OTHER buffer
//      after compute, ONE barrier per chunk (was 2).
//   3. LDS 32.6KB, lb(256,3) (R8 lesson: avoid the 128-reg 4-wave cliff).
// kB / kC / kInit unchanged (proven).
// ---------------------------------------------------------------------------

using s16x8 = __attribute__((ext_vector_type(8))) short;
using f32x4 = __attribute__((ext_vector_type(4))) float;
using f32x2 = __attribute__((ext_vector_type(2))) float;

__device__ __forceinline__ float leaky(float x) {
    return x >= 0.f ? x : 0.01f * x;
}

__device__ __forceinline__ unsigned short f2bf(float f) {
    unsigned x = __float_as_uint(f);
    return (unsigned short)((x + 0x7FFFu + ((x >> 16) & 1u)) >> 16);
}

// ---------------------------------------------------------------------------
// kInit: zero ta accumulators; transpose bw1/bw2 for kC; pack conv1/conv2
// weights for kA.
// ---------------------------------------------------------------------------
__global__ void kInit(float* __restrict__ sums, unsigned* __restrict__ maxu,
                      const float* __restrict__ bw1, const float* __restrict__ bw2,
                      const float* __restrict__ fw1, const float* __restrict__ fw2,
                      float* __restrict__ wT1g, float* __restrict__ wT2g,
                      float2* __restrict__ wsW1, short* __restrict__ wsW) {
    int t = threadIdx.x;   // 256
    sums[t] = 0.f;
    maxu[t] = 0u;
    for (int i = t; i < 288; i += 256) {
        int o = i & 15, rest = i >> 4;
        int ic = rest / 9, k = rest - ic * 9;
        wT1g[i] = bw1[(o * 2 + ic) * 9 + k];
    }
    for (int i = t; i < 2304; i += 256) {
        int o = i & 15, rest = i >> 4;
        int ic = rest / 9, k = rest - ic * 9;
        wT2g[i] = bw2[(o * 16 + ic) * 9 + k];
    }
    // conv1 weights: wsW1[(c4*36) + q*4 + cl] = (wy, wm) of channel 4*c4+cl
    for (int i = t; i < 1008; i += 256) {
        int c4 = i / 36, rem = i - c4 * 36;
        int q = rem >> 2, cl = rem & 3;
        int ch = c4 * 4 + cl;
        wsW1[i] = make_float2(fw1[ch * 18 + q], fw1[ch * 18 + 9 + q]);
    }
    // conv2 weights: bf16 [64][128], K zero-padded 112..127
    for (int i = t; i < 8192; i += 256) {
        int o = i >> 7, k = i & 127;
        wsW[i] = (k < 112) ? (short)f2bf(fw2[o * 112 + k]) : (short)0;
    }
}

// ---------------------------------------------------------------------------
// kA: fused conv1(grouped 3x3, pk_fma) + conv2(1x1, MFMA) + xc + ta reduce.
// Grid (16,32,8): 8x16 tiles. Block 256 = 4 waves; wave wv owns rows
// 2wv..2wv+1, lane (col,lq): pixel x=col, k-slice lq.
// Halo LDS: SoA planes, col-major stride 10, DOUBLE-BUFFERED.
// ---------------------------------------------------------------------------
__global__ __launch_bounds__(256, 3) void kA(
    const float* __restrict__ y, const float* __restrict__ mask,
    const float* __restrict__ fb1, const float* __restrict__ fb2,
    const float2* __restrict__ wsW1, const short* __restrict__ wsW,
    float* __restrict__ xc, float* __restrict__ sums, unsigned* __restrict__ maxu)
{
    __shared__ float  shY[2][1440];              // y halo dbuf     11520B
    __shared__ float  shM[2][1440];              // mask halo dbuf  11520B
    __shared__ __align__(16) float2 w1q4[1008];  // conv1 W          8064B
    __shared__ __align__(16) float  fbl[112];    // conv1 bias        448B
    __shared__ float  red[4 * 32 * 2];           // ta partials      1024B

    const int b  = blockIdx.z;
    const int h0 = blockIdx.y << 3;
    const int w0 = blockIdx.x << 4;
    const int tid = threadIdx.x;
    const int wv = tid >> 6, ln = tid & 63;
    const int col = ln & 15, lq = ln >> 4;

    // ---- weight staging: plain copies (packed by kInit) ----
    #pragma unroll
    for (int j = 0; j < 4; ++j) {
        int i = tid + j * 256;
        if (i < 1008) w1q4[i] = wsW1[i];
    }
    if (tid < 112) fbl[tid] = fb1[tid];

    // ---- staging slots: ROW-major global walk, col-major LDS cell ----
    int  sOff[7], sLds[7];
    bool sOK[7];
    #pragma unroll
    for (int j = 0; j < 7; ++j) {
        const int i = tid + j * 256;
        int gl = i / 180, rem = i - gl * 180;
        int r = rem / 18, c = rem - r * 18;      // row-major walk (coalesced)
        int gh = h0 + r - 1, gw = w0 + c - 1;
        sOK[j]  = (i < 1440) && ((unsigned)gh < 256u) && ((unsigned)gw < 256u);
        sOff[j] = ((b * 28 + gl) << 16) + (gh << 8) + gw;
        sLds[j] = gl * 180 + c * 10 + r;         // col-major store, stride 10
    }

    // ---- prologue: load + publish chunk 0 into buffer 0 ----
    float2 pf[7];
    #pragma unroll
    for (int j = 0; j < 7; ++j) {
        pf[j] = make_float2(0.f, 0.f);
        if (sOK[j]) {
            size_t o = (size_t)sOff[j];
            pf[j].x = y[o];
            pf[j].y = mask[o];
        }
    }
    #pragma unroll
    for (int j = 0; j < 7; ++j) {
        if (tid + j * 256 < 1440) {
            shY[0][sLds[j]] = pf[j].x;
            shM[0][sLds[j]] = pf[j].y;
        }
    }

    // ---- C accumulators, init with conv2 bias ----
    f32x4 acc[2][4];   // [pg][t]
    #pragma unroll
    for (int t = 0; t < 4; ++t) {
        #pragma unroll
        for (int r = 0; r < 4; ++r) {
            float bv = fb2[t * 16 + lq * 4 + r];
            acc[0][t][r] = bv;
            acc[1][t][r] = bv;
        }
    }
    __syncthreads();   // chunk-0 halo + weights visible

    // ---- K-chunk loop, double-buffered: 1 barrier per chunk ----
    #pragma unroll 1
    for (int s = 0; s < 4; ++s) {
        const int cur = s & 1;

        // issue next chunk's loads NOW (latency hides under compute below)
        const int TOTn = (s == 2) ? 720 : 1440;
        if (s < 3) {
            const int chAdd = ((s + 1) * 8) << 16;
            #pragma unroll
            for (int j = 0; j < 7; ++j) {
                pf[j] = make_float2(0.f, 0.f);
                if (sOK[j] && (tid + j * 256) < TOTn) {
                    size_t o = (size_t)(sOff[j] + chAdd);
                    pf[j].x = y[o];
                    pf[j].y = mask[o];
                }
            }
        }

        // A-fragments direct from global (L2-resident)
        s16x8 A[4];
        #pragma unroll
        for (int t = 0; t < 4; ++t)
            A[t] = *(const s16x8*)&wsW[(t * 16 + col) * 128 + s * 32 + lq * 8];

        // ---- conv1 -> B-fragments (pk_fma over the 2 output rows) ----
        unsigned Bu[2][4] = {{0u,0u,0u,0u},{0u,0u,0u,0u}};

        if (s < 3 || lq < 2) {             // s=3, lq>=2 -> channels >=112
            #pragma unroll
            for (int gidx = 0; gidx < 2; ++gidx) {
                const int gl = 2 * lq + gidx;      // local group 0..7
                const int c4 = s * 8 + gl;         // global channel-quad
                const float* bY = &shY[cur][gl * 180 + col * 10 + 2 * wv];
                const float* bM = &shM[cur][gl * 180 + col * 10 + 2 * wv];
                float hYv[3][4], hMv[3][4];        // [col][row]
                #pragma unroll
                for (int cc = 0; cc < 3; ++cc)
                    #pragma unroll
                    for (int rr = 0; rr < 4; ++rr) {
                        hYv[cc][rr] = bY[cc * 10 + rr];
                        hMv[cc][rr] = bM[cc * 10 + rr];
                    }

                const f32x4 bias4 = *(const f32x4*)&fbl[c4 * 4];
                f32x2 a0 = {bias4[0], bias4[0]};
                f32x2 a1 = {bias4[1], bias4[1]};
                f32x2 a2 = {bias4[2], bias4[2]};
                f32x2 a3 = {bias4[3], bias4[3]};
                const f32x4* wquad = (const f32x4*)&w1q4[c4 * 36];
                #pragma unroll
                for (int q = 0; q < 9; ++q) {
                    const int dy = q / 3, dx = q % 3;
                    const f32x4 wa = wquad[2 * q];       // wy0,wm0,wy1,wm1
                    const f32x4 wb = wquad[2 * q + 1];   // wy2,wm2,wy3,wm3
                    f32x2 hy = {hYv[dx][dy], hYv[dx][dy + 1]};
                    f32x2 hm = {hMv[dx][dy], hMv[dx][dy + 1]};
                    a0 += hy * wa[0] + hm * wa[1];
                    a1 += hy * wa[2] + hm * wa[3];
                    a2 += hy * wb[0] + hm * wb[1];
                    a3 += hy * wb[2] + hm * wb[3];
                }
                const float r00 = fmaxf(a0[0], 0.f), r01 = fmaxf(a1[0], 0.f);
                const float r02 = fmaxf(a2[0], 0.f), r03 = fmaxf(a3[0], 0.f);
                const float r10 = fmaxf(a0[1], 0.f), r11 = fmaxf(a1[1], 0.f);
                const float r12 = fmaxf(a2[1], 0.f), r13 = fmaxf(a3[1], 0.f);
                unsigned p0lo, p0hi, p1lo, p1hi;
                asm("v_cvt_pk_bf16_f32 %0, %1, %2" : "=v"(p0lo) : "v"(r00), "v"(r01));
                asm("v_cvt_pk_bf16_f32 %0, %1, %2" : "=v"(p0hi) : "v"(r02), "v"(r03));
                asm("v_cvt_pk_bf16_f32 %0, %1, %2" : "=v"(p1lo) : "v"(r10), "v"(r11));
                asm("v_cvt_pk_bf16_f32 %0, %1, %2" : "=v"(p1hi) : "v"(r12), "v"(r13));
                Bu[0][gidx * 2 + 0] = p0lo;
                Bu[0][gidx * 2 + 1] = p0hi;
                Bu[1][gidx * 2 + 0] = p1lo;
                Bu[1][gidx * 2 + 1] = p1hi;
            }
        }

        s16x8 Bf[2];
        #pragma unroll
        for (int pg = 0; pg < 2; ++pg) {
            union { unsigned u[4]; s16x8 v; } cvt;
            cvt.u[0] = Bu[pg][0]; cvt.u[1] = Bu[pg][1];
            cvt.u[2] = Bu[pg][2]; cvt.u[3] = Bu[pg][3];
            Bf[pg] = cvt.v;
        }

        #pragma unroll
        for (int pg = 0; pg < 2; ++pg)
            #pragma unroll
            for (int t = 0; t < 4; ++t)
                acc[pg][t] = __builtin_amdgcn_mfma_f32_16x16x32_bf16(
                                 A[t], Bf[pg], acc[pg][t], 0, 0, 0);

        // ---- publish prefetched chunk into the OTHER buffer ----
        if (s < 3) {
            #pragma unroll
            for (int j = 0; j < 7; ++j) {
                if (tid + j * 256 < TOTn) {
                    shY[cur ^ 1][sLds[j]] = pf[j].x;
                    shM[cur ^ 1][sLds[j]] = pf[j].y;
                }
            }
            __syncthreads();   // next-chunk halo visible to all waves
        }
    }

    // ---- epilogue (proven rounds 3-10) ----
    float* xc0 = xc + (((size_t)b * 2) << 16);
    float* xc1 = xc0 + 65536;

    float run_s[2][4], run_m[2][4];
    #pragma unroll
    for (int t = 0; t < 2; ++t)
        #pragma unroll
        for (int r = 0; r < 4; ++r) { run_s[t][r] = 0.f; run_m[t][r] = -3.4e38f; }

    #pragma unroll
    for (int pg = 0; pg < 2; ++pg) {
        float m8 = -3.4e38f, s8 = 0.f;
        #pragma unroll
        for (int t = 2; t < 4; ++t)
            #pragma unroll
            for (int r = 0; r < 4; ++r) {
                float v = acc[pg][t][r];
                m8 = fmaxf(m8, v); s8 += v;
            }
        m8 = fmaxf(m8, __shfl_xor(m8, 16));
        m8 = fmaxf(m8, __shfl_xor(m8, 32));
        s8 += __shfl_xor(s8, 16);
        s8 += __shfl_xor(s8, 32);
        if (ln < 16) {
            int row = h0 + 2 * wv + pg;
            xc0[(row << 8) + w0 + ln] = m8;
            xc1[(row << 8) + w0 + ln] = s8 * (1.f / 32.f);
        }
        #pragma unroll
        for (int t = 0; t < 2; ++t)
            #pragma unroll
            for (int r = 0; r < 4; ++r) {
                float v = acc[pg][t][r];
                run_s[t][r] += v;
                run_m[t][r] = fmaxf(run_m[t][r], v);
            }
    }

    #pragma unroll
    for (int t = 0; t < 2; ++t)
        #pragma unroll
        for (int r = 0; r < 4; ++r) {
            float s = run_s[t][r], m = run_m[t][r];
            #pragma unroll
            for (int off = 1; off < 16; off <<= 1) {
                s += __shfl_xor(s, off);
                m = fmaxf(m, __shfl_xor(m, off));
            }
            if (col == 0) {
                int ch = t * 16 + lq * 4 + r;
                red[(wv * 32 + ch) * 2 + 0] = s;
                red[(wv * 32 + ch) * 2 + 1] = m;
            }
        }
    __syncthreads();
    if (tid < 32) {
        float s = red[tid*2] + red[(32+tid)*2] + red[(64+tid)*2] + red[(96+tid)*2];
        float m = fmaxf(fmaxf(red[tid*2+1], red[(32+tid)*2+1]),
                        fmaxf(red[(64+tid)*2+1], red[(96+tid)*2+1]));
        atomicAdd(&sums[b*32 + tid], s);
        unsigned ub  = __float_as_uint(m);
        unsigned key = (ub & 0x80000000u) ? ~ub : (ub | 0x80000000u);
        atomicMax(&maxu[b*32 + tid], key);
    }
}

// ---------------------------------------------------------------------------
// Kernel B: finish ta mean/max, run pgm MLP on both, alpha = sum.
// ---------------------------------------------------------------------------
__global__ __launch_bounds__(256) void kB(
    const float* __restrict__ sums, const unsigned* __restrict__ maxu,
    const float* __restrict__ aw1, const float* __restrict__ ab1,
    const float* __restrict__ aw2, const float* __restrict__ ab2,
    const float* __restrict__ aw3, const float* __restrict__ ab3,
    float* __restrict__ out)
{
    __shared__ float xa[8][32], xm[8][32], h1a[8][32], h1m[8][32];
    const int tid = threadIdx.x;
    const int b = tid >> 5, i = tid & 31;

    xa[b][i] = sums[b*32 + i] * (1.f/65536.f);
    unsigned u = maxu[b*32 + i];
    unsigned bits = (u & 0x80000000u) ? (u ^ 0x80000000u) : ~u;
    xm[b][i] = __uint_as_float(bits);
    __syncthreads();

    float sa = ab1[i], sm = ab1[i];
    #pragma unroll
    for (int j = 0; j < 32; ++j) {
        float w = aw1[i*32 + j];
        sa += w * xa[b][j]; sm += w * xm[b][j];
    }
    __syncthreads();
    h1a[b][i] = leaky(sa); h1m[b][i] = leaky(sm);
    __syncthreads();

    sa = ab2[i]; sm = ab2[i];
    #pragma unroll
    for (int j = 0; j < 32; ++j) {
        float w = aw2[i*32 + j];
        sa += w * h1a[b][j]; sm += w * h1m[b][j];
    }
    float h2a = leaky(sa), h2m = leaky(sm);

    float pa = aw3[i] * h2a, pm = aw3[i] * h2m;
    #pragma unroll
    for (int off = 16; off > 0; off >>= 1) {
        pa += __shfl_xor(pa, off);
        pm += __shfl_xor(pm, off);
    }
    if (i == 0) {
        float za = fmaxf(pa + ab3[0], 0.f) + 1e-6f;
        float zm = fmaxf(pm + ab3[0], 0.f) + 1e-6f;
        out[b] = za + zm;
    }
}

// ---------------------------------------------------------------------------
// kC: fused beta chain, spill-free (round-7 proven).
// ---------------------------------------------------------------------------
__global__ __launch_bounds__(256, 3) void kC(
    const float* __restrict__ xc,
    const float* __restrict__ wT1g, const float* __restrict__ bb1,
    const float* __restrict__ wT2g, const float* __restrict__ bb2,
    const float* __restrict__ bw3, const float* __restrict__ bb3,
    float* __restrict__ betaout)
{
    __shared__ float shX[2 * 484];
    __shared__ float shB1[16 * 400];
    __shared__ float shB2[16 * 324];

    const int b  = blockIdx.z;
    const int h0 = blockIdx.y << 4;
    const int w0 = blockIdx.x << 4;
    const int tid = threadIdx.x;

    for (int i = tid; i < 968; i += 256) {
        int ch = i / 484, rem = i - ch * 484;
        int r = rem / 22, c = rem - r * 22;
        int gh = h0 + r - 3, gw = w0 + c - 3;
        float v = 0.f;
        if ((unsigned)gh < 256u && (unsigned)gw < 256u)
            v = xc[(((size_t)b * 2 + ch) << 16) + (gh << 8) + gw];
        shX[i] = v;
    }
    __syncthreads();

    const f32x4 bias1_0 = *(const f32x4*)&bb1[0];
    const f32x4 bias1_1 = *(const f32x4*)&bb1[4];
    const f32x4 bias1_2 = *(const f32x4*)&bb1[8];
    const f32x4 bias1_3 = *(const f32x4*)&bb1[12];
    #pragma unroll 1
    for (int p = tid; p < 400; p += 256) {
        int r1 = p / 20, c1 = p - r1 * 20;
        f32x4 a0 = bias1_0, a1 = bias1_1, a2 = bias1_2, a3 = bias1_3;
        #pragma unroll
        for (int ic = 0; ic < 2; ++ic)
            #pragma unroll
            for (int k = 0; k < 9; ++k) {
                float v = shX[ic * 484 + (r1 + k / 3) * 22 + (c1 + k % 3)];
                const f32x4* wp = (const f32x4*)&wT1g[(ic * 9 + k) << 4];
                a0 += wp[0] * v; a1 += wp[1] * v;
                a2 += wp[2] * v; a3 += wp[3] * v;
            }
        int gh = h0 - 2 + r1, gw = w0 - 2 + c1;
        if (((unsigned)gh < 256u) && ((unsigned)gw < 256u)) {
            shB1[ 0*400+p]=leaky(a0[0]); shB1[ 1*400+p]=leaky(a0[1]);
            shB1[ 2*400+p]=leaky(a0[2]); shB1[ 3*400+p]=leaky(a0[3]);
            shB1[ 4*400+p]=leaky(a1[0]); shB1[ 5*400+p]=leaky(a1[1]);
            shB1[ 6*400+p]=leaky(a1[2]); shB1[ 7*400+p]=leaky(a1[3]);
            shB1[ 8*400+p]=leaky(a2[0]); shB1[ 9*400+p]=leaky(a2[1]);
            shB1[10*400+p]=leaky(a2[2]); shB1[11*400+p]=leaky(a2[3]);
            shB1[12*400+p]=leaky(a3[0]); shB1[13*400+p]=leaky(a3[1]);
            shB1[14*400+p]=leaky(a3[2]); shB1[15*400+p]=leaky(a3[3]);
        } else {
            #pragma unroll
            for (int o = 0; o < 16; ++o) shB1[o*400+p] = 0.f;
        }
    }
    __syncthreads();

    const f32x4 bias2_0 = *(const f32x4*)&bb2[0];
    const f32x4 bias2_1 = *(const f32x4*)&bb2[4];
    const f32x4 bias2_2 = *(const f32x4*)&bb2[8];
    const f32x4 bias2_3 = *(const f32x4*)&bb2[12];
    #pragma unroll 1
    for (int p = tid; p < 324; p += 256) {
        int r2 = p / 18, c2 = p - r2 * 18;
        f32x4 a0 = bias2_0, a1 = bias2_1, a2 = bias2_2, a3 = bias2_3;
        #pragma unroll 2
        for (int ic = 0; ic < 16; ++ic) {
            const float* base = &shB1[ic * 400 + r2 * 20 + c2];
            #pragma unroll
            for (int k = 0; k < 9; ++k) {
                float v = base[(k / 3) * 20 + (k % 3)];
                const f32x4* wp = (const f32x4*)&wT2g[(ic * 9 + k) << 4];
                a0 += wp[0] * v; a1 += wp[1] * v;
                a2 += wp[2] * v; a3 += wp[3] * v;
            }
        }
        int gh = h0 - 1 + r2, gw = w0 - 1 + c2;
        if (((unsigned)gh < 256u) && ((unsigned)gw < 256u)) {
            shB2[ 0*324+p]=leaky(a0[0]); shB2[ 1*324+p]=leaky(a0[1]);
            shB2[ 2*324+p]=leaky(a0[2]); shB2[ 3*324+p]=leaky(a0[3]);
            shB2[ 4*324+p]=leaky(a1[0]); shB2[ 5*324+p]=leaky(a1[1]);
            shB2[ 6*324+p]=leaky(a1[2]); shB2[ 7*324+p]=leaky(a1[3]);
            shB2[ 8*324+p]=leaky(a2[0]); shB2[ 9*324+p]=leaky(a2[1]);
            shB2[10*324+p]=leaky(a2[2]); shB2[11*324+p]=leaky(a2[3]);
            shB2[12*324+p]=leaky(a3[0]); shB2[13*324+p]=leaky(a3[1]);
            shB2[14*324+p]=leaky(a3[2]); shB2[15*324+p]=leaky(a3[3]);
        } else {
            #pragma unroll
            for (int o = 0; o < 16; ++o) shB2[o*324+p] = 0.f;
        }
    }
    __syncthreads();

    {
        int r3 = tid >> 4, c3 = tid & 15;
        float a = bb3[0];
        #pragma unroll 4
        for (int ic = 0; ic < 16; ++ic)
            #pragma unroll
            for (int k = 0; k < 9; ++k)
                a += bw3[ic * 9 + k]
                     * shB2[ic * 324 + (r3 + k / 3) * 18 + (c3 + k % 3)];
        betaout[((size_t)b << 16) + ((h0 + r3) << 8) + (w0 + c3)]
            = 1.f / (1.f + expf(-a));
    }
}

// ---------------------------------------------------------------------------
extern "C" void kernel_launch(void* const* d_in, const int* in_sizes, int n_in,
                              void* d_out, int out_size, void* d_ws, size_t ws_size,
                              hipStream_t stream) {
    const float* y    = (const float*)d_in[0];
    const float* mask = (const float*)d_in[1];
    const float* fw1  = (const float*)d_in[2];
    const float* fb1  = (const float*)d_in[3];
    const float* fw2  = (const float*)d_in[4];
    const float* fb2  = (const float*)d_in[5];
    const float* aw1  = (const float*)d_in[6];
    const float* ab1  = (const float*)d_in[7];
    const float* aw2  = (const float*)d_in[8];
    const float* ab2  = (const float*)d_in[9];
    const float* aw3  = (const float*)d_in[10];
    const float* ab3  = (const float*)d_in[11];
    const float* bw1  = (const float*)d_in[12];
    const float* bb1  = (const float*)d_in[13];
    const float* bw2  = (const float*)d_in[14];
    const float* bb2  = (const float*)d_in[15];
    const float* bw3  = (const float*)d_in[16];
    const float* bb3  = (const float*)d_in[17];
    float* out = (float*)d_out;

    char* ws = (char*)d_ws;
    float*    sums = (float*)ws;                 // 1 KB
    unsigned* maxu = (unsigned*)(ws + 1024);     // 1 KB
    float*    wT1g = (float*)(ws + 2048);        // 1152 B
    float*    wT2g = (float*)(ws + 3200);        // 9216 B (ends 12416)
    float2*   wsW1 = (float2*)(ws + 12416);      // 8064 B (ends 20480)
    short*    wsW  = (short*)(ws + 20480);       // 16384 B (ends 36864)
    float*    xc   = (float*)(ws + 65536);       // 4 MB

    kInit<<<1, 256, 0, stream>>>(sums, maxu, bw1, bw2, fw1, fw2,
                                 wT1g, wT2g, wsW1, wsW);
    kA<<<dim3(16, 32, 8), 256, 0, stream>>>(y, mask, fb1, fb2, wsW1, wsW,
                                            xc, sums, maxu);
    kB<<<1, 256, 0, stream>>>(sums, maxu, aw1, ab1, aw2, ab2, aw3, ab3, out);
    kC<<<dim3(16, 16, 8), 256, 0, stream>>>(xc, wT1g, bb1, wT2g, bb2, bw3, bb3,
                                            out + 8);
}

// Round 12
// 201.815 us; speedup vs baseline: 1.6728x; 1.0606x over previous
//
#include <hip/hip_runtime.h>
#include <hip/hip_bf16.h>
#include <math.h>

// ---------------------------------------------------------------------------
// HyperParamNet — round 12.
// Round-11 landed (kA 125us, fetch-volume-bound: 216MB @ 1.8TB/s = wall).
// Over-fetch (216 vs 117MB input) = halo lines fetched by 2-3 adjacent
// tiles that round-robin onto DIFFERENT XCDs (per-XCD L2 not shared).
// This round (T1, single change): XCD-chunked block swizzle in kA —
// flat grid 4096, wg = (orig&7)*512 + orig>>3 -> each XCD processes one
// full batch (14.7MB stream, ~600KB live strip << 4MB L2). All halo reuse
// becomes XCD-local L2 hits. Bijective (4096%8==0). Rest byte-identical.
// ---------------------------------------------------------------------------

using s16x8 = __attribute__((ext_vector_type(8))) short;
using f32x4 = __attribute__((ext_vector_type(4))) float;
using f32x2 = __attribute__((ext_vector_type(2))) float;

__device__ __forceinline__ float leaky(float x) {
    return x >= 0.f ? x : 0.01f * x;
}

__device__ __forceinline__ unsigned short f2bf(float f) {
    unsigned x = __float_as_uint(f);
    return (unsigned short)((x + 0x7FFFu + ((x >> 16) & 1u)) >> 16);
}

// ---------------------------------------------------------------------------
// kInit: zero ta accumulators; transpose bw1/bw2 for kC; pack conv1/conv2
// weights for kA.
// ---------------------------------------------------------------------------
__global__ void kInit(float* __restrict__ sums, unsigned* __restrict__ maxu,
                      const float* __restrict__ bw1, const float* __restrict__ bw2,
                      const float* __restrict__ fw1, const float* __restrict__ fw2,
                      float* __restrict__ wT1g, float* __restrict__ wT2g,
                      float2* __restrict__ wsW1, short* __restrict__ wsW) {
    int t = threadIdx.x;   // 256
    sums[t] = 0.f;
    maxu[t] = 0u;
    for (int i = t; i < 288; i += 256) {
        int o = i & 15, rest = i >> 4;
        int ic = rest / 9, k = rest - ic * 9;
        wT1g[i] = bw1[(o * 2 + ic) * 9 + k];
    }
    for (int i = t; i < 2304; i += 256) {
        int o = i & 15, rest = i >> 4;
        int ic = rest / 9, k = rest - ic * 9;
        wT2g[i] = bw2[(o * 16 + ic) * 9 + k];
    }
    // conv1 weights: wsW1[(c4*36) + q*4 + cl] = (wy, wm) of channel 4*c4+cl
    for (int i = t; i < 1008; i += 256) {
        int c4 = i / 36, rem = i - c4 * 36;
        int q = rem >> 2, cl = rem & 3;
        int ch = c4 * 4 + cl;
        wsW1[i] = make_float2(fw1[ch * 18 + q], fw1[ch * 18 + 9 + q]);
    }
    // conv2 weights: bf16 [64][128], K zero-padded 112..127
    for (int i = t; i < 8192; i += 256) {
        int o = i >> 7, k = i & 127;
        wsW[i] = (k < 112) ? (short)f2bf(fw2[o * 112 + k]) : (short)0;
    }
}

// ---------------------------------------------------------------------------
// kA: fused conv1(grouped 3x3, pk_fma) + conv2(1x1, MFMA) + xc + ta reduce.
// Flat grid 4096, XCD-chunked swizzle: XCD k (= orig%8 round-robin) gets
// wg in [512k, 512k+512) = one full batch. Tile decode: b=wg>>9,
// by=(wg>>4)&31, bx=wg&15. Block 256 = 4 waves; wave wv owns rows
// 2wv..2wv+1, lane (col,lq): pixel x=col, k-slice lq.
// ---------------------------------------------------------------------------
__global__ __launch_bounds__(256, 3) void kA(
    const float* __restrict__ y, const float* __restrict__ mask,
    const float* __restrict__ fb1, const float* __restrict__ fb2,
    const float2* __restrict__ wsW1, const short* __restrict__ wsW,
    float* __restrict__ xc, float* __restrict__ sums, unsigned* __restrict__ maxu)
{
    __shared__ float  shY[2][1440];              // y halo dbuf     11520B
    __shared__ float  shM[2][1440];              // mask halo dbuf  11520B
    __shared__ __align__(16) float2 w1q4[1008];  // conv1 W          8064B
    __shared__ __align__(16) float  fbl[112];    // conv1 bias        448B
    __shared__ float  red[4 * 32 * 2];           // ta partials      1024B

    // ---- XCD-chunked swizzle (bijective: 4096 % 8 == 0) ----
    const int orig = blockIdx.x;
    const int wg   = (orig & 7) * 512 + (orig >> 3);
    const int b    = wg >> 9;
    const int h0   = ((wg >> 4) & 31) << 3;
    const int w0   = (wg & 15) << 4;

    const int tid = threadIdx.x;
    const int wv = tid >> 6, ln = tid & 63;
    const int col = ln & 15, lq = ln >> 4;

    // ---- weight staging: plain copies (packed by kInit) ----
    #pragma unroll
    for (int j = 0; j < 4; ++j) {
        int i = tid + j * 256;
        if (i < 1008) w1q4[i] = wsW1[i];
    }
    if (tid < 112) fbl[tid] = fb1[tid];

    // ---- staging slots: ROW-major global walk, col-major LDS cell ----
    int  sOff[7], sLds[7];
    bool sOK[7];
    #pragma unroll
    for (int j = 0; j < 7; ++j) {
        const int i = tid + j * 256;
        int gl = i / 180, rem = i - gl * 180;
        int r = rem / 18, c = rem - r * 18;      // row-major walk (coalesced)
        int gh = h0 + r - 1, gw = w0 + c - 1;
        sOK[j]  = (i < 1440) && ((unsigned)gh < 256u) && ((unsigned)gw < 256u);
        sOff[j] = ((b * 28 + gl) << 16) + (gh << 8) + gw;
        sLds[j] = gl * 180 + c * 10 + r;         // col-major store, stride 10
    }

    // ---- prologue: load + publish chunk 0 into buffer 0 ----
    float2 pf[7];
    #pragma unroll
    for (int j = 0; j < 7; ++j) {
        pf[j] = make_float2(0.f, 0.f);
        if (sOK[j]) {
            size_t o = (size_t)sOff[j];
            pf[j].x = y[o];
            pf[j].y = mask[o];
        }
    }
    #pragma unroll
    for (int j = 0; j < 7; ++j) {
        if (tid + j * 256 < 1440) {
            shY[0][sLds[j]] = pf[j].x;
            shM[0][sLds[j]] = pf[j].y;
        }
    }

    // ---- C accumulators, init with conv2 bias ----
    f32x4 acc[2][4];   // [pg][t]
    #pragma unroll
    for (int t = 0; t < 4; ++t) {
        #pragma unroll
        for (int r = 0; r < 4; ++r) {
            float bv = fb2[t * 16 + lq * 4 + r];
            acc[0][t][r] = bv;
            acc[1][t][r] = bv;
        }
    }
    __syncthreads();   // chunk-0 halo + weights visible

    // ---- K-chunk loop, double-buffered: 1 barrier per chunk ----
    #pragma unroll 1
    for (int s = 0; s < 4; ++s) {
        const int cur = s & 1;

        // issue next chunk's loads NOW (latency hides under compute below)
        const int TOTn = (s == 2) ? 720 : 1440;
        if (s < 3) {
            const int chAdd = ((s + 1) * 8) << 16;
            #pragma unroll
            for (int j = 0; j < 7; ++j) {
                pf[j] = make_float2(0.f, 0.f);
                if (sOK[j] && (tid + j * 256) < TOTn) {
                    size_t o = (size_t)(sOff[j] + chAdd);
                    pf[j].x = y[o];
                    pf[j].y = mask[o];
                }
            }
        }

        // A-fragments direct from global (L2-resident)
        s16x8 A[4];
        #pragma unroll
        for (int t = 0; t < 4; ++t)
            A[t] = *(const s16x8*)&wsW[(t * 16 + col) * 128 + s * 32 + lq * 8];

        // ---- conv1 -> B-fragments (pk_fma over the 2 output rows) ----
        unsigned Bu[2][4] = {{0u,0u,0u,0u},{0u,0u,0u,0u}};

        if (s < 3 || lq < 2) {             // s=3, lq>=2 -> channels >=112
            #pragma unroll
            for (int gidx = 0; gidx < 2; ++gidx) {
                const int gl = 2 * lq + gidx;      // local group 0..7
                const int c4 = s * 8 + gl;         // global channel-quad
                const float* bY = &shY[cur][gl * 180 + col * 10 + 2 * wv];
                const float* bM = &shM[cur][gl * 180 + col * 10 + 2 * wv];
                float hYv[3][4], hMv[3][4];        // [col][row]
                #pragma unroll
                for (int cc = 0; cc < 3; ++cc)
                    #pragma unroll
                    for (int rr = 0; rr < 4; ++rr) {
                        hYv[cc][rr] = bY[cc * 10 + rr];
                        hMv[cc][rr] = bM[cc * 10 + rr];
                    }

                const f32x4 bias4 = *(const f32x4*)&fbl[c4 * 4];
                f32x2 a0 = {bias4[0], bias4[0]};
                f32x2 a1 = {bias4[1], bias4[1]};
                f32x2 a2 = {bias4[2], bias4[2]};
                f32x2 a3 = {bias4[3], bias4[3]};
                const f32x4* wquad = (const f32x4*)&w1q4[c4 * 36];
                #pragma unroll
                for (int q = 0; q < 9; ++q) {
                    const int dy = q / 3, dx = q % 3;
                    const f32x4 wa = wquad[2 * q];       // wy0,wm0,wy1,wm1
                    const f32x4 wb = wquad[2 * q + 1];   // wy2,wm2,wy3,wm3
                    f32x2 hy = {hYv[dx][dy], hYv[dx][dy + 1]};
                    f32x2 hm = {hMv[dx][dy], hMv[dx][dy + 1]};
                    a0 += hy * wa[0] + hm * wa[1];
                    a1 += hy * wa[2] + hm * wa[3];
                    a2 += hy * wb[0] + hm * wb[1];
                    a3 += hy * wb[2] + hm * wb[3];
                }
                const float r00 = fmaxf(a0[0], 0.f), r01 = fmaxf(a1[0], 0.f);
                const float r02 = fmaxf(a2[0], 0.f), r03 = fmaxf(a3[0], 0.f);
                const float r10 = fmaxf(a0[1], 0.f), r11 = fmaxf(a1[1], 0.f);
                const float r12 = fmaxf(a2[1], 0.f), r13 = fmaxf(a3[1], 0.f);
                unsigned p0lo, p0hi, p1lo, p1hi;
                asm("v_cvt_pk_bf16_f32 %0, %1, %2" : "=v"(p0lo) : "v"(r00), "v"(r01));
                asm("v_cvt_pk_bf16_f32 %0, %1, %2" : "=v"(p0hi) : "v"(r02), "v"(r03));
                asm("v_cvt_pk_bf16_f32 %0, %1, %2" : "=v"(p1lo) : "v"(r10), "v"(r11));
                asm("v_cvt_pk_bf16_f32 %0, %1, %2" : "=v"(p1hi) : "v"(r12), "v"(r13));
                Bu[0][gidx * 2 + 0] = p0lo;
                Bu[0][gidx * 2 + 1] = p0hi;
                Bu[1][gidx * 2 + 0] = p1lo;
                Bu[1][gidx * 2 + 1] = p1hi;
            }
        }

        s16x8 Bf[2];
        #pragma unroll
        for (int pg = 0; pg < 2; ++pg) {
            union { unsigned u[4]; s16x8 v; } cvt;
            cvt.u[0] = Bu[pg][0]; cvt.u[1] = Bu[pg][1];
            cvt.u[2] = Bu[pg][2]; cvt.u[3] = Bu[pg][3];
            Bf[pg] = cvt.v;
        }

        #pragma unroll
        for (int pg = 0; pg < 2; ++pg)
            #pragma unroll
            for (int t = 0; t < 4; ++t)
                acc[pg][t] = __builtin_amdgcn_mfma_f32_16x16x32_bf16(
                                 A[t], Bf[pg], acc[pg][t], 0, 0, 0);

        // ---- publish prefetched chunk into the OTHER buffer ----
        if (s < 3) {
            #pragma unroll
            for (int j = 0; j < 7; ++j) {
                if (tid + j * 256 < TOTn) {
                    shY[cur ^ 1][sLds[j]] = pf[j].x;
                    shM[cur ^ 1][sLds[j]] = pf[j].y;
                }
            }
            __syncthreads();   // next-chunk halo visible to all waves
        }
    }

    // ---- epilogue (proven rounds 3-11) ----
    float* xc0 = xc + (((size_t)b * 2) << 16);
    float* xc1 = xc0 + 65536;

    float run_s[2][4], run_m[2][4];
    #pragma unroll
    for (int t = 0; t < 2; ++t)
        #pragma unroll
        for (int r = 0; r < 4; ++r) { run_s[t][r] = 0.f; run_m[t][r] = -3.4e38f; }

    #pragma unroll
    for (int pg = 0; pg < 2; ++pg) {
        float m8 = -3.4e38f, s8 = 0.f;
        #pragma unroll
        for (int t = 2; t < 4; ++t)
            #pragma unroll
            for (int r = 0; r < 4; ++r) {
                float v = acc[pg][t][r];
                m8 = fmaxf(m8, v); s8 += v;
            }
        m8 = fmaxf(m8, __shfl_xor(m8, 16));
        m8 = fmaxf(m8, __shfl_xor(m8, 32));
        s8 += __shfl_xor(s8, 16);
        s8 += __shfl_xor(s8, 32);
        if (ln < 16) {
            int row = h0 + 2 * wv + pg;
            xc0[(row << 8) + w0 + ln] = m8;
            xc1[(row << 8) + w0 + ln] = s8 * (1.f / 32.f);
        }
        #pragma unroll
        for (int t = 0; t < 2; ++t)
            #pragma unroll
            for (int r = 0; r < 4; ++r) {
                float v = acc[pg][t][r];
                run_s[t][r] += v;
                run_m[t][r] = fmaxf(run_m[t][r], v);
            }
    }

    #pragma unroll
    for (int t = 0; t < 2; ++t)
        #pragma unroll
        for (int r = 0; r < 4; ++r) {
            float s = run_s[t][r], m = run_m[t][r];
            #pragma unroll
            for (int off = 1; off < 16; off <<= 1) {
                s += __shfl_xor(s, off);
                m = fmaxf(m, __shfl_xor(m, off));
            }
            if (col == 0) {
                int ch = t * 16 + lq * 4 + r;
                red[(wv * 32 + ch) * 2 + 0] = s;
                red[(wv * 32 + ch) * 2 + 1] = m;
            }
        }
    __syncthreads();
    if (tid < 32) {
        float s = red[tid*2] + red[(32+tid)*2] + red[(64+tid)*2] + red[(96+tid)*2];
        float m = fmaxf(fmaxf(red[tid*2+1], red[(32+tid)*2+1]),
                        fmaxf(red[(64+tid)*2+1], red[(96+tid)*2+1]));
        atomicAdd(&sums[b*32 + tid], s);
        unsigned ub  = __float_as_uint(m);
        unsigned key = (ub & 0x80000000u) ? ~ub : (ub | 0x80000000u);
        atomicMax(&maxu[b*32 + tid], key);
    }
}

// ---------------------------------------------------------------------------
// Kernel B: finish ta mean/max, run pgm MLP on both, alpha = sum.
// ---------------------------------------------------------------------------
__global__ __launch_bounds__(256) void kB(
    const float* __restrict__ sums, const unsigned* __restrict__ maxu,
    const float* __restrict__ aw1, const float* __restrict__ ab1,
    const float* __restrict__ aw2, const float* __restrict__ ab2,
    const float* __restrict__ aw3, const float* __restrict__ ab3,
    float* __restrict__ out)
{
    __shared__ float xa[8][32], xm[8][32], h1a[8][32], h1m[8][32];
    const int tid = threadIdx.x;
    const int b = tid >> 5, i = tid & 31;

    xa[b][i] = sums[b*32 + i] * (1.f/65536.f);
    unsigned u = maxu[b*32 + i];
    unsigned bits = (u & 0x80000000u) ? (u ^ 0x80000000u) : ~u;
    xm[b][i] = __uint_as_float(bits);
    __syncthreads();

    float sa = ab1[i], sm = ab1[i];
    #pragma unroll
    for (int j = 0; j < 32; ++j) {
        float w = aw1[i*32 + j];
        sa += w * xa[b][j]; sm += w * xm[b][j];
    }
    __syncthreads();
    h1a[b][i] = leaky(sa); h1m[b][i] = leaky(sm);
    __syncthreads();

    sa = ab2[i]; sm = ab2[i];
    #pragma unroll
    for (int j = 0; j < 32; ++j) {
        float w = aw2[i*32 + j];
        sa += w * h1a[b][j]; sm += w * h1m[b][j];
    }
    float h2a = leaky(sa), h2m = leaky(sm);

    float pa = aw3[i] * h2a, pm = aw3[i] * h2m;
    #pragma unroll
    for (int off = 16; off > 0; off >>= 1) {
        pa += __shfl_xor(pa, off);
        pm += __shfl_xor(pm, off);
    }
    if (i == 0) {
        float za = fmaxf(pa + ab3[0], 0.f) + 1e-6f;
        float zm = fmaxf(pm + ab3[0], 0.f) + 1e-6f;
        out[b] = za + zm;
    }
}

// ---------------------------------------------------------------------------
// kC: fused beta chain, spill-free (round-7 proven).
// ---------------------------------------------------------------------------
__global__ __launch_bounds__(256, 3) void kC(
    const float* __restrict__ xc,
    const float* __restrict__ wT1g, const float* __restrict__ bb1,
    const float* __restrict__ wT2g, const float* __restrict__ bb2,
    const float* __restrict__ bw3, const float* __restrict__ bb3,
    float* __restrict__ betaout)
{
    __shared__ float shX[2 * 484];
    __shared__ float shB1[16 * 400];
    __shared__ float shB2[16 * 324];

    const int b  = blockIdx.z;
    const int h0 = blockIdx.y << 4;
    const int w0 = blockIdx.x << 4;
    const int tid = threadIdx.x;

    for (int i = tid; i < 968; i += 256) {
        int ch = i / 484, rem = i - ch * 484;
        int r = rem / 22, c = rem - r * 22;
        int gh = h0 + r - 3, gw = w0 + c - 3;
        float v = 0.f;
        if ((unsigned)gh < 256u && (unsigned)gw < 256u)
            v = xc[(((size_t)b * 2 + ch) << 16) + (gh << 8) + gw];
        shX[i] = v;
    }
    __syncthreads();

    const f32x4 bias1_0 = *(const f32x4*)&bb1[0];
    const f32x4 bias1_1 = *(const f32x4*)&bb1[4];
    const f32x4 bias1_2 = *(const f32x4*)&bb1[8];
    const f32x4 bias1_3 = *(const f32x4*)&bb1[12];
    #pragma unroll 1
    for (int p = tid; p < 400; p += 256) {
        int r1 = p / 20, c1 = p - r1 * 20;
        f32x4 a0 = bias1_0, a1 = bias1_1, a2 = bias1_2, a3 = bias1_3;
        #pragma unroll
        for (int ic = 0; ic < 2; ++ic)
            #pragma unroll
            for (int k = 0; k < 9; ++k) {
                float v = shX[ic * 484 + (r1 + k / 3) * 22 + (c1 + k % 3)];
                const f32x4* wp = (const f32x4*)&wT1g[(ic * 9 + k) << 4];
                a0 += wp[0] * v; a1 += wp[1] * v;
                a2 += wp[2] * v; a3 += wp[3] * v;
            }
        int gh = h0 - 2 + r1, gw = w0 - 2 + c1;
        if (((unsigned)gh < 256u) && ((unsigned)gw < 256u)) {
            shB1[ 0*400+p]=leaky(a0[0]); shB1[ 1*400+p]=leaky(a0[1]);
            shB1[ 2*400+p]=leaky(a0[2]); shB1[ 3*400+p]=leaky(a0[3]);
            shB1[ 4*400+p]=leaky(a1[0]); shB1[ 5*400+p]=leaky(a1[1]);
            shB1[ 6*400+p]=leaky(a1[2]); shB1[ 7*400+p]=leaky(a1[3]);
            shB1[ 8*400+p]=leaky(a2[0]); shB1[ 9*400+p]=leaky(a2[1]);
            shB1[10*400+p]=leaky(a2[2]); shB1[11*400+p]=leaky(a2[3]);
            shB1[12*400+p]=leaky(a3[0]); shB1[13*400+p]=leaky(a3[1]);
            shB1[14*400+p]=leaky(a3[2]); shB1[15*400+p]=leaky(a3[3]);
        } else {
            #pragma unroll
            for (int o = 0; o < 16; ++o) shB1[o*400+p] = 0.f;
        }
    }
    __syncthreads();

    const f32x4 bias2_0 = *(const f32x4*)&bb2[0];
    const f32x4 bias2_1 = *(const f32x4*)&bb2[4];
    const f32x4 bias2_2 = *(const f32x4*)&bb2[8];
    const f32x4 bias2_3 = *(const f32x4*)&bb2[12];
    #pragma unroll 1
    for (int p = tid; p < 324; p += 256) {
        int r2 = p / 18, c2 = p - r2 * 18;
        f32x4 a0 = bias2_0, a1 = bias2_1, a2 = bias2_2, a3 = bias2_3;
        #pragma unroll 2
        for (int ic = 0; ic < 16; ++ic) {
            const float* base = &shB1[ic * 400 + r2 * 20 + c2];
            #pragma unroll
            for (int k = 0; k < 9; ++k) {
                float v = base[(k / 3) * 20 + (k % 3)];
                const f32x4* wp = (const f32x4*)&wT2g[(ic * 9 + k) << 4];
                a0 += wp[0] * v; a1 += wp[1] * v;
                a2 += wp[2] * v; a3 += wp[3] * v;
            }
        }
        int gh = h0 - 1 + r2, gw = w0 - 1 + c2;
        if (((unsigned)gh < 256u) && ((unsigned)gw < 256u)) {
            shB2[ 0*324+p]=leaky(a0[0]); shB2[ 1*324+p]=leaky(a0[1]);
            shB2[ 2*324+p]=leaky(a0[2]); shB2[ 3*324+p]=leaky(a0[3]);
            shB2[ 4*324+p]=leaky(a1[0]); shB2[ 5*324+p]=leaky(a1[1]);
            shB2[ 6*324+p]=leaky(a1[2]); shB2[ 7*324+p]=leaky(a1[3]);
            shB2[ 8*324+p]=leaky(a2[0]); shB2[ 9*324+p]=leaky(a2[1]);
            shB2[10*324+p]=leaky(a2[2]); shB2[11*324+p]=leaky(a2[3]);
            shB2[12*324+p]=leaky(a3[0]); shB2[13*324+p]=leaky(a3[1]);
            shB2[14*324+p]=leaky(a3[2]); shB2[15*324+p]=leaky(a3[3]);
        } else {
            #pragma unroll
            for (int o = 0; o < 16; ++o) shB2[o*324+p] = 0.f;
        }
    }
    __syncthreads();

    {
        int r3 = tid >> 4, c3 = tid & 15;
        float a = bb3[0];
        #pragma unroll 4
        for (int ic = 0; ic < 16; ++ic)
            #pragma unroll
            for (int k = 0; k < 9; ++k)
                a += bw3[ic * 9 + k]
                     * shB2[ic * 324 + (r3 + k / 3) * 18 + (c3 + k % 3)];
        betaout[((size_t)b << 16) + ((h0 + r3) << 8) + (w0 + c3)]
            = 1.f / (1.f + expf(-a));
    }
}

// ---------------------------------------------------------------------------
extern "C" void kernel_launch(void* const* d_in, const int* in_sizes, int n_in,
                              void* d_out, int out_size, void* d_ws, size_t ws_size,
                              hipStream_t stream) {
    const float* y    = (const float*)d_in[0];
    const float* mask = (const float*)d_in[1];
    const float* fw1  = (const float*)d_in[2];
    const float* fb1  = (const float*)d_in[3];
    const float* fw2  = (const float*)d_in[4];
    const float* fb2  = (const float*)d_in[5];
    const float* aw1  = (const float*)d_in[6];
    const float* ab1  = (const float*)d_in[7];
    const float* aw2  = (const float*)d_in[8];
    const float* ab2  = (const float*)d_in[9];
    const float* aw3  = (const float*)d_in[10];
    const float* ab3  = (const float*)d_in[11];
    const float* bw1  = (const float*)d_in[12];
    const float* bb1  = (const float*)d_in[13];
    const float* bw2  = (const float*)d_in[14];
    const float* bb2  = (const float*)d_in[15];
    const float* bw3  = (const float*)d_in[16];
    const float* bb3  = (const float*)d_in[17];
    float* out = (float*)d_out;

    char* ws = (char*)d_ws;
    float*    sums = (float*)ws;                 // 1 KB
    unsigned* maxu = (unsigned*)(ws + 1024);     // 1 KB
    float*    wT1g = (float*)(ws + 2048);        // 1152 B
    float*    wT2g = (float*)(ws + 3200);        // 9216 B (ends 12416)
    float2*   wsW1 = (float2*)(ws + 12416);      // 8064 B (ends 20480)
    short*    wsW  = (short*)(ws + 20480);       // 16384 B (ends 36864)
    float*    xc   = (float*)(ws + 65536);       // 4 MB

    kInit<<<1, 256, 0, stream>>>(sums, maxu, bw1, bw2, fw1, fw2,
                                 wT1g, wT2g, wsW1, wsW);
    kA<<<4096, 256, 0, stream>>>(y, mask, fb1, fb2, wsW1, wsW,
                                 xc, sums, maxu);
    kB<<<1, 256, 0, stream>>>(sums, maxu, aw1, ab1, aw2, ab2, aw3, ab3, out);
    kC<<<dim3(16, 16, 8), 256, 0, stream>>>(xc, wT1g, bb1, wT2g, bb2, bw3, bb3,
                                            out + 8);
}